// Round 21
// baseline (718.569 us; speedup 1.0000x reference)
//
#include <hip/hip_runtime.h>
#include <math.h>

// ---------------- sizes ----------------
#define NB 32
#define HID 256
#define HW1 (63*63)      // 3969
#define HW2 (62*62)      // 3844
#define T63 ((size_t)NB*HID*HW1)   // 32,514,048
#define T62 ((size_t)NB*HID*HW2)   // 31,490,048
#define NROWS 123008               // T62 / 256
#define KCB 512
#define GATHER_BLOCKS 1024

typedef __attribute__((ext_vector_type(8))) short short8;
typedef __attribute__((ext_vector_type(4))) float f32x4;
typedef __attribute__((ext_vector_type(4))) unsigned short us4;

__device__ __forceinline__ unsigned short f2bf(float f) {
    union { float f; unsigned int u; } v; v.f = f;
    unsigned int u = v.u;
    return (unsigned short)((u + 0x7FFFu + ((u >> 16) & 1u)) >> 16);
}
__device__ __forceinline__ float bf2f(unsigned short u) {
    union { unsigned int i; float f; } v; v.i = ((unsigned int)u) << 16;
    return v.f;
}

// ---------------- zero helpers ----------------
__global__ __launch_bounds__(256) void zero_small(float* __restrict__ sse, int* __restrict__ counts) {
    if (threadIdx.x == 0) sse[0] = 0.f;
    for (int i = threadIdx.x; i < KCB; i += 256) counts[i] = 0;
}

// ---------------- conv1 weight prepack ----------------
__global__ __launch_bounds__(256) void prepack_c1(
    const float* __restrict__ w, unsigned short* __restrict__ pack) {
    int t = blockIdx.x*256 + threadIdx.x;
    if (t >= 16384) return;
    int j = t & 7, lk = (t >> 3) & 3, co = (t >> 5) & 255, kc = t >> 13;
    int k = kc*32 + lk*8 + j;
    pack[t] = (k < 48) ? f2bf(w[co*48 + k]) : (unsigned short)0;
}

// ---------------- conv1: 3->256, k4, s2, relu -> bf16 NHWC via im2col MFMA; fused GAP partials ----------------
__global__ __launch_bounds__(256) void conv1_mfma(
    const float* __restrict__ x, const unsigned short* __restrict__ apack,
    const float* __restrict__ bias, unsigned short* __restrict__ X0,
    float* __restrict__ poolp) {
    __shared__ float xs[3][18][18];
    __shared__ __align__(16) unsigned short Bm[64*72];
    int b = blockIdx.y, t = blockIdx.x;
    int oh0 = (t >> 3)*8, ow0 = (t & 7)*8;
    int ih0 = oh0*2, iw0 = ow0*2;
    const float* xb = x + (size_t)b*3*128*128;
    for (int i = threadIdx.x; i < 972; i += 256) {
        int c = i / 324, rem = i - c*324, r = rem / 18, cl = rem - r*18;
        int ih = ih0 + r, iw = iw0 + cl;
        xs[c][r][cl] = (ih < 128 && iw < 128) ? xb[((size_t)c*128 + ih)*128 + iw] : 0.f;
    }
    __syncthreads();
    for (int i = threadIdx.x; i < 2048; i += 256) {
        int px = i >> 5, kp = (i & 31)*2;
        int ph = px >> 3, pw = px & 7;
        unsigned int pk = 0;
        #pragma unroll
        for (int u = 0; u < 2; ++u) {
            int k = kp + u;
            float v = 0.f;
            if (k < 48) {
                int c = k >> 4, k2 = k & 15, kh = k2 >> 2, kw = k2 & 3;
                v = xs[c][ph*2+kh][pw*2+kw];
            }
            pk |= ((unsigned int)f2bf(v)) << (16*u);
        }
        *(unsigned int*)&Bm[px*72 + kp] = pk;
    }
    __syncthreads();

    int w = threadIdx.x >> 6, l = threadIdx.x & 63;
    int lr = l & 15, lk = l >> 4;
    f32x4 acc[4][4];
    #pragma unroll
    for (int i = 0; i < 4; ++i)
        #pragma unroll
        for (int j = 0; j < 4; ++j) acc[i][j] = (f32x4){0.f,0.f,0.f,0.f};

    #pragma unroll
    for (int kc = 0; kc < 2; ++kc) {
        short8 bf[4];
        #pragma unroll
        for (int pxf = 0; pxf < 4; ++pxf)
            bf[pxf] = *(const short8*)&Bm[(pxf*16+lr)*72 + kc*32 + lk*8];
        #pragma unroll
        for (int cof = 0; cof < 4; ++cof) {
            int co = w*64 + cof*16 + lr;
            short8 af = *(const short8*)(apack + (((size_t)kc*256 + co)*4 + (size_t)lk)*8);
            acc[cof][0] = __builtin_amdgcn_mfma_f32_16x16x32_bf16(af, bf[0], acc[cof][0], 0, 0, 0);
            acc[cof][1] = __builtin_amdgcn_mfma_f32_16x16x32_bf16(af, bf[1], acc[cof][1], 0, 0, 0);
            acc[cof][2] = __builtin_amdgcn_mfma_f32_16x16x32_bf16(af, bf[2], acc[cof][2], 0, 0, 0);
            acc[cof][3] = __builtin_amdgcn_mfma_f32_16x16x32_bf16(af, bf[3], acc[cof][3], 0, 0, 0);
        }
    }
    float gsum[4][4];
    #pragma unroll
    for (int i = 0; i < 4; ++i)
        #pragma unroll
        for (int j = 0; j < 4; ++j) gsum[i][j] = 0.f;
    #pragma unroll
    for (int cof = 0; cof < 4; ++cof) {
        int cob = w*64 + cof*16 + lk*4;
        float4 bz = *(const float4*)&bias[cob];
        #pragma unroll
        for (int pxf = 0; pxf < 4; ++pxf) {
            int px = pxf*16 + lr;
            int oh = oh0 + (px >> 3), ow = ow0 + (px & 7);
            if (oh < 63 && ow < 63) {
                f32x4 a = acc[cof][pxf];
                float r0 = fmaxf(a.x + bz.x, 0.f);
                float r1 = fmaxf(a.y + bz.y, 0.f);
                float r2 = fmaxf(a.z + bz.z, 0.f);
                float r3 = fmaxf(a.w + bz.w, 0.f);
                gsum[cof][0] += r0; gsum[cof][1] += r1;
                gsum[cof][2] += r2; gsum[cof][3] += r3;
                us4 pk = { f2bf(r0), f2bf(r1), f2bf(r2), f2bf(r3) };
                *(us4*)(X0 + ((size_t)b*HW1 + (size_t)oh*63 + ow)*256 + cob) = pk;
            }
        }
    }
    #pragma unroll
    for (int cof = 0; cof < 4; ++cof)
        #pragma unroll
        for (int j = 0; j < 4; ++j) {
            #pragma unroll
            for (int m = 1; m < 16; m <<= 1)
                gsum[cof][j] += __shfl_xor(gsum[cof][j], m, 64);
        }
    if (lr == 0) {
        float* dst = poolp + ((size_t)b*64 + blockIdx.x)*256;
        #pragma unroll
        for (int cof = 0; cof < 4; ++cof)
            #pragma unroll
            for (int j = 0; j < 4; ++j)
                dst[w*64 + cof*16 + lk*4 + j] = gsum[cof][j] * (1.f/HW1);
    }
}

// ---------------- SE MLP (sums `parts` partial slices) ----------------
__global__ __launch_bounds__(256) void se_mlp(
    const float* __restrict__ pooled, const float* __restrict__ w1,
    const float* __restrict__ b1, const float* __restrict__ w2,
    const float* __restrict__ b2, float* __restrict__ g, int parts) {
    int b = blockIdx.x;
    __shared__ float ps[256], hs[16];
    float s = 0.f;
    for (int k = 0; k < parts; ++k)
        s += pooled[((size_t)b*parts + k)*256 + threadIdx.x];
    ps[threadIdx.x] = s;
    __syncthreads();
    if (threadIdx.x < 16) {
        float a = b1[threadIdx.x];
        const float* wr = w1 + threadIdx.x*256;
        for (int k = 0; k < 256; ++k) a = fmaf(ps[k], wr[k], a);
        hs[threadIdx.x] = fmaxf(a, 0.f);
    }
    __syncthreads();
    float a = b2[threadIdx.x];
    const float* wr = w2 + threadIdx.x*16;
    #pragma unroll
    for (int j = 0; j < 16; ++j) a = fmaf(hs[j], wr[j], a);
    g[b*256 + threadIdx.x] = 1.f / (1.f + expf(-a));
}

// ---------------- channel mean/max of x*g (NHWC bf16) ----------------
__global__ __launch_bounds__(256) void chanpool_nhwc(
    const unsigned short* __restrict__ X, const float* __restrict__ g,
    float* __restrict__ am, int HW) {
    int b = blockIdx.y;
    __shared__ float gs[256];
    gs[threadIdx.x] = g[b*256 + threadIdx.x];
    __syncthreads();
    int p = blockIdx.x*256 + threadIdx.x;
    if (p >= HW) return;
    const unsigned short* xp = X + ((size_t)b*HW + p)*256;
    float s = 0.f, mx = -3.0e38f;
    for (int o = 0; o < 32; ++o) {
        short8 v = *(const short8*)(xp + o*8);
        #pragma unroll
        for (int j = 0; j < 8; ++j) {
            float f = bf2f((unsigned short)v[j]) * gs[o*8+j];
            s += f; mx = fmaxf(mx, f);
        }
    }
    am[((size_t)b*2)*HW + p]   = s * (1.f/256.f);
    am[((size_t)b*2+1)*HW + p] = mx;
}

// ---------------- channel mean/max of x*g (bf16 NCHW, encoder-2 z) ----------------
__global__ __launch_bounds__(256) void chanpool_z(
    const unsigned short* __restrict__ Z, const float* __restrict__ g,
    float* __restrict__ am, int HW) {
    int b = blockIdx.y;
    __shared__ float gs[256];
    gs[threadIdx.x] = g[b*256 + threadIdx.x];
    __syncthreads();
    int p = blockIdx.x*256 + threadIdx.x;
    if (p >= HW) return;
    const unsigned short* xb = Z + (size_t)b*256*HW + p;
    float s = 0.f, mx = -3.0e38f;
    for (int c = 0; c < 256; ++c) {
        float v = bf2f(xb[(size_t)c*HW]) * gs[c];
        s += v; mx = fmaxf(mx, v);
    }
    am[((size_t)b*2)*HW + p]   = s * (1.f/256.f);
    am[((size_t)b*2+1)*HW + p] = mx;
}

// ---------------- 7x7 spatial conv on [mean,max], sigmoid ----------------
__global__ __launch_bounds__(256) void spatial_conv(
    const float* __restrict__ am, const float* __restrict__ sw,
    float* __restrict__ ss, int H, int W, int transpose) {
    int b = blockIdx.y;
    int p = blockIdx.x*256 + threadIdx.x;
    __shared__ float ws[98];
    if (threadIdx.x < 98) {
        int c = threadIdx.x / 49, k = threadIdx.x % 49;
        int kh = k / 7, kw = k % 7;
        ws[threadIdx.x] = transpose ? sw[c*49 + (6-kh)*7 + (6-kw)]
                                    : sw[c*49 + kh*7 + kw];
    }
    __syncthreads();
    if (p >= H*W) return;
    int oh = p / W, ow = p % W;
    float acc = 0.f;
    #pragma unroll
    for (int c = 0; c < 2; ++c) {
        const float* ab = am + ((size_t)b*2 + c)*H*W;
        for (int kh = 0; kh < 7; ++kh) {
            int ih = oh + kh - 3;
            if (ih < 0 || ih >= H) continue;
            for (int kw = 0; kw < 7; ++kw) {
                int iw = ow + kw - 3;
                if (iw < 0 || iw >= W) continue;
                acc = fmaf(ab[(size_t)ih*W + iw], ws[c*49 + kh*7 + kw], acc);
            }
        }
    }
    ss[(size_t)b*H*W + p] = 1.f / (1.f + expf(-acc));
}

// ---------------- bf16 NCHW -> NHWC bf16 (q after VQ) ----------------
__global__ __launch_bounds__(256) void to_nhwc_bf16(
    const unsigned short* __restrict__ Z, unsigned short* __restrict__ X, int HW) {
    int b = blockIdx.y;
    int p = blockIdx.x*256 + threadIdx.x;
    bool valid = p < HW;
    const unsigned short* inb = Z + (size_t)b*256*HW + p;
    unsigned short* dst = X + ((size_t)b*HW + p)*256;
    #pragma unroll
    for (int ch = 0; ch < 4; ++ch) {
        unsigned short buf[64];
        #pragma unroll
        for (int j = 0; j < 64; ++j)
            buf[j] = valid ? inb[(size_t)(ch*64 + j)*HW] : (unsigned short)0;
        if (valid) {
            #pragma unroll
            for (int j2 = 0; j2 < 8; ++j2)
                *(short8*)(dst + ch*64 + j2*8) = *(const short8*)&buf[j2*8];
        }
    }
}

// ---------------- weight prepack into MFMA-fragment layout (bf16) ----------------
__global__ __launch_bounds__(256) void prepack_w(
    const float* __restrict__ w, unsigned short* __restrict__ pack, int transpose_flip) {
    int t = blockIdx.x*256 + threadIdx.x;
    int j = t & 7, koct = (t >> 3) & 3, co = (t >> 5) & 255, tap = (t >> 13) & 3, cc = t >> 15;
    int ci = cc*32 + koct*8 + j;
    int kh = tap >> 1, kw = tap & 1;
    float v;
    if (transpose_flip) v = w[((size_t)ci*256 + co)*4 + (1-kh)*2 + (1-kw)];
    else                v = w[((size_t)co*256 + ci)*4 + kh*2 + kw];
    pack[t] = f2bf(v);
}

// ---------------- dt2 weight prepack (MFMA A-frag) ----------------
__global__ __launch_bounds__(256) void prepack_dt2b(
    const float* __restrict__ w, unsigned short* __restrict__ pk) {
    int t = blockIdx.x*256 + threadIdx.x;
    int jj = t & 7, lk = (t >> 3) & 3, co = (t >> 5) & 15, j = (t >> 9) & 3, cc = (t >> 11) & 7, p = t >> 14;
    int ci = cc*32 + lk*8 + jj;
    int kh0 = p >> 1, kw0 = p & 1;
    const int dj[4] = {0, 2, 8, 10};
    float v = 0.f;
    if (co < 3) v = w[(size_t)ci*48 + co*16 + kh0*4 + kw0 + dj[j]];
    pk[t] = f2bf(v);
}

// ---------------- MFMA conv k=2 s=1, NHWC bf16 input, 4x16 tiles, BK=64, XCD swizzle; fused GAP ----------------
// MODE 0: fused input cbam multiply (x*x*g*ss), bf16 NCHW out (conv2 -> z).
// MODE 1: plain input, bf16 NHWC out via LDS-staged epilogue (dt1).
template <int MODE>
__global__ __launch_bounds__(256) void convk2_mfma_nhwc(
    const unsigned short* __restrict__ Xin, const unsigned short* __restrict__ apack,
    const float* __restrict__ bias, const float* __restrict__ gvec,
    const float* __restrict__ ssm, unsigned short* __restrict__ outZ,
    unsigned short* __restrict__ outU,
    float* __restrict__ poolp,
    int inH, int inW, int outH, int outW, int pad) {
    __shared__ __align__(16) unsigned short Sh[MODE ? 16896 : 13600];
    __shared__ float gs[256];
    unsigned short* Ir0 = Sh;
    unsigned short* Ir1 = Sh + 6800;
    int b = blockIdx.y;
    int raw = blockIdx.x;
    int xcd = raw & 7, jj = raw >> 3;
    int t = (xcd + 8*(jj >> 2))*4 + (jj & 3);
    int oh0 = (t >> 2) * 4, ow0 = (t & 3) * 16;
    int w = threadIdx.x >> 6, l = threadIdx.x & 63;
    int lr = l & 15, lk = l >> 4;
    const unsigned short* src = Xin + (size_t)b*inH*inW*256;
    const float* ssb = (MODE == 0) ? (ssm + (size_t)b*inH*inW) : (const float*)0;
    if (MODE == 0) {
        gs[threadIdx.x] = gvec[b*256 + threadIdx.x];
        __syncthreads();
    }

    f32x4 acc[4][4];
    #pragma unroll
    for (int i = 0; i < 4; ++i)
        #pragma unroll
        for (int j = 0; j < 4; ++j) acc[i][j] = (f32x4){0.f,0.f,0.f,0.f};

    auto STAGE = [&](int cc, int bufi) {
        unsigned short* Ib = bufi ? Ir1 : Ir0;
        #pragma unroll
        for (int pass = 0; pass < 3; ++pass) {
            int u = pass*256 + threadIdx.x;
            if (u < 680) {
                int sub = (u >= 340) ? 1 : 0;
                int uu = u - sub*340;
                int sp = uu >> 2, q = uu & 3;
                int r = (sp*241) >> 12, c = sp - r*17;
                int gh = oh0 + r - pad, gw = ow0 + c - pad;
                short8 v = (short8){0,0,0,0,0,0,0,0};
                bool valid = (gh >= 0) && (gh < inH) && (gw >= 0) && (gw < inW);
                if (valid)
                    v = *(const short8*)(src + ((size_t)gh*inW + gw)*256 + (cc+sub)*32 + q*8);
                if (MODE == 0) {
                    if (valid) {
                        float sv = ssb[(size_t)gh*inW + gw];
                        int c0 = (cc+sub)*32 + q*8;
                        unsigned int pk[4];
                        #pragma unroll
                        for (int j = 0; j < 4; ++j) {
                            float f0 = bf2f((unsigned short)v[2*j]);
                            float f1 = bf2f((unsigned short)v[2*j+1]);
                            f0 = f0*f0*gs[c0+2*j]*sv;
                            f1 = f1*f1*gs[c0+2*j+1]*sv;
                            pk[j] = (unsigned int)f2bf(f0) | ((unsigned int)f2bf(f1) << 16);
                        }
                        v = *(const short8*)pk;
                    }
                }
                *(short8*)&Ib[sub*3400 + sp*40 + q*8] = v;
            }
        }
    };

    STAGE(0, 0);
    for (int cc = 0; cc < 8; cc += 2) {
        __syncthreads();
        if (cc < 6) STAGE(cc+2, ((cc >> 1) + 1) & 1);
        const unsigned short* Ibase = ((cc >> 1) & 1) ? Ir1 : Ir0;
        #pragma unroll
        for (int half = 0; half < 2; ++half) {
            const unsigned short* Ib = Ibase + half*3400;
            #pragma unroll
            for (int tap = 0; tap < 4; ++tap) {
                int kh = tap >> 1, kw = tap & 1;
                int spb = kh*17 + kw + lr;
                short8 b0 = *(const short8*)&Ib[(spb     )*40 + lk*8];
                short8 b1 = *(const short8*)&Ib[(spb + 17)*40 + lk*8];
                short8 b2 = *(const short8*)&Ib[(spb + 34)*40 + lk*8];
                short8 b3 = *(const short8*)&Ib[(spb + 51)*40 + lk*8];
                const unsigned short* abase = apack + (((size_t)((cc+half)*4 + tap)*256)*4 + (size_t)lk)*8;
                #pragma unroll
                for (int cof = 0; cof < 4; ++cof) {
                    int co = w*64 + cof*16 + lr;
                    short8 af = *(const short8*)(abase + (size_t)co*32);
                    acc[cof][0] = __builtin_amdgcn_mfma_f32_16x16x32_bf16(af, b0, acc[cof][0], 0, 0, 0);
                    acc[cof][1] = __builtin_amdgcn_mfma_f32_16x16x32_bf16(af, b1, acc[cof][1], 0, 0, 0);
                    acc[cof][2] = __builtin_amdgcn_mfma_f32_16x16x32_bf16(af, b2, acc[cof][2], 0, 0, 0);
                    acc[cof][3] = __builtin_amdgcn_mfma_f32_16x16x32_bf16(af, b3, acc[cof][3], 0, 0, 0);
                }
            }
        }
    }
    float gsum[4][4];
    #pragma unroll
    for (int i = 0; i < 4; ++i)
        #pragma unroll
        for (int j = 0; j < 4; ++j) gsum[i][j] = 0.f;
    int ow = ow0 + lr;
    if (MODE == 0) {
        #pragma unroll
        for (int cof = 0; cof < 4; ++cof) {
            int cob = w*64 + cof*16 + lk*4;
            float4 bz = *(const float4*)&bias[cob];
            #pragma unroll
            for (int pxf = 0; pxf < 4; ++pxf) {
                int oh = oh0 + pxf;
                if (oh < outH && ow < outW) {
                    f32x4 a = acc[cof][pxf];
                    float r0 = fmaxf(a.x + bz.x, 0.f);
                    float r1 = fmaxf(a.y + bz.y, 0.f);
                    float r2 = fmaxf(a.z + bz.z, 0.f);
                    float r3 = fmaxf(a.w + bz.w, 0.f);
                    gsum[cof][0] += r0; gsum[cof][1] += r1;
                    gsum[cof][2] += r2; gsum[cof][3] += r3;
                    size_t base = ((size_t)(b*256 + cob)*outH + oh)*outW + ow;
                    size_t st = (size_t)outH*outW;
                    outZ[base]        = f2bf(r0);
                    outZ[base +   st] = f2bf(r1);
                    outZ[base + 2*st] = f2bf(r2);
                    outZ[base + 3*st] = f2bf(r3);
                }
            }
        }
    } else {
        __syncthreads();
        #pragma unroll
        for (int cof = 0; cof < 4; ++cof) {
            int cob = w*64 + cof*16 + lk*4;
            float4 bz = *(const float4*)&bias[cob];
            #pragma unroll
            for (int pxf = 0; pxf < 4; ++pxf) {
                f32x4 a = acc[cof][pxf];
                float r0 = fmaxf(a.x + bz.x, 0.f);
                float r1 = fmaxf(a.y + bz.y, 0.f);
                float r2 = fmaxf(a.z + bz.z, 0.f);
                float r3 = fmaxf(a.w + bz.w, 0.f);
                int oh = oh0 + pxf;
                if (oh < outH && ow < outW) {
                    gsum[cof][0] += r0; gsum[cof][1] += r1;
                    gsum[cof][2] += r2; gsum[cof][3] += r3;
                }
                us4 pk = { f2bf(r0), f2bf(r1), f2bf(r2), f2bf(r3) };
                *(us4*)&Sh[(pxf*16 + lr)*264 + cob] = pk;
            }
        }
        __syncthreads();
        int owp = threadIdx.x >> 4, c0 = (threadIdx.x & 15)*16;
        int oww = ow0 + owp;
        #pragma unroll
        for (int row = 0; row < 4; ++row) {
            int oh = oh0 + row;
            if (oh < outH && oww < outW) {
                unsigned short* dst = outU + (((size_t)b*outH + oh)*outW + oww)*256 + c0;
                *(short8*)dst       = *(const short8*)&Sh[(row*16 + owp)*264 + c0];
                *(short8*)(dst + 8) = *(const short8*)&Sh[(row*16 + owp)*264 + c0 + 8];
            }
        }
    }
    #pragma unroll
    for (int cof = 0; cof < 4; ++cof)
        #pragma unroll
        for (int j = 0; j < 4; ++j) {
            #pragma unroll
            for (int m = 1; m < 16; m <<= 1)
                gsum[cof][j] += __shfl_xor(gsum[cof][j], m, 64);
        }
    if (lr == 0) {
        float inv = 1.f / (float)(outH * outW);
        float* dst = poolp + ((size_t)b*64 + raw)*256;
        #pragma unroll
        for (int cof = 0; cof < 4; ++cof)
            #pragma unroll
            for (int j = 0; j < 4; ++j)
                dst[w*64 + cof*16 + lk*4 + j] = gsum[cof][j] * inv;
    }
}

// ---------------- codebook norms ----------------
__global__ __launch_bounds__(256) void cb_norm(
    const float* __restrict__ cb, float* __restrict__ cbn) {
    for (int n = threadIdx.x; n < KCB; n += 256) {
        float s = 0.f;
        for (int k = 0; k < 256; ++k) { float v = cb[(size_t)n*256+k]; s = fmaf(v,v,s); }
        cbn[n] = s;
    }
}

// ---------------- codebook bf16 pack ----------------
__global__ __launch_bounds__(256) void cb_pack(
    const float* __restrict__ cb, unsigned short* __restrict__ cbp) {
    int t = blockIdx.x*256 + threadIdx.x;
    cbp[t] = f2bf(cb[t]);
}

// ---------------- MFMA VQ assign: fused cbam-z multiply in staging; bf16 z, LDS codebook ----------------
__global__ __launch_bounds__(256) void vq_assign_mfma(
    const unsigned short* __restrict__ z, const unsigned short* __restrict__ cbp,
    const float* __restrict__ cbn, const float* __restrict__ gvec,
    const float* __restrict__ ssm, int* __restrict__ idx) {
    __shared__ __align__(16) unsigned short zb[64*264];
    __shared__ __align__(16) unsigned short cbs[2][32*264];
    __shared__ float cbl[KCB];
    int r0 = blockIdx.x * 64;
    const unsigned int PB = 256u * HW2;
    for (int v = threadIdx.x; v < 2048; v += 256) {
        int row = v >> 5, o = v & 31;
        unsigned int flat = (unsigned int)(r0 + row)*256u + o*8;
        short8 zraw = *(const short8*)&z[flat];
        unsigned int bb = flat / PB;
        unsigned int rem = flat - bb*PB;
        unsigned int c = rem / (unsigned)HW2;
        unsigned int p = rem - c*(unsigned)HW2;
        const float* gb = gvec + bb*256;
        const float* sb = ssm + (size_t)bb*HW2;
        unsigned short buf[8];
        #pragma unroll
        for (int j = 0; j < 8; ++j) {
            float f = bf2f((unsigned short)zraw[j]);
            f = f*f*gb[c]*sb[p];
            buf[j] = f2bf(f);
            if (++p == (unsigned)HW2) {
                p = 0;
                if (++c == 256u) { c = 0; gb += 256; sb += HW2; }
            }
        }
        *(short8*)&zb[row*264 + o*8] = *(const short8*)buf;
    }
    for (int i = threadIdx.x; i < KCB; i += 256) cbl[i] = cbn[i];
    int tcode = threadIdx.x >> 3, tk = threadIdx.x & 7;
    auto STAGE_CB = [&](int c, int bufi) {
        const unsigned short* src = cbp + ((size_t)(c*32 + tcode))*256 + tk*8;
        unsigned short* dst = &cbs[bufi][tcode*264 + tk*8];
        #pragma unroll
        for (int j = 0; j < 4; ++j)
            *(short8*)(dst + j*64) = *(const short8*)(src + j*64);
    };
    STAGE_CB(0, 0);
    __syncthreads();

    int w = threadIdx.x >> 6, l = threadIdx.x & 63;
    int lr = l & 15, lk = l >> 4;
    short8 afr[8];
    #pragma unroll
    for (int ks = 0; ks < 8; ++ks)
        afr[ks] = *(const short8*)&zb[(w*16 + lr)*264 + ks*32 + lk*8];

    float bd[4]; int bi[4];
    #pragma unroll
    for (int r = 0; r < 4; ++r) { bd[r] = 3.0e38f; bi[r] = 0; }

    for (int c = 0; c < 16; ++c) {
        if (c < 15) STAGE_CB(c+1, (c+1)&1);
        const unsigned short* Cb = cbs[c & 1];
        #pragma unroll
        for (int f = 0; f < 2; ++f) {
            f32x4 acc = (f32x4){0.f,0.f,0.f,0.f};
            #pragma unroll
            for (int ks = 0; ks < 8; ++ks) {
                short8 bfr = *(const short8*)&Cb[(f*16 + lr)*264 + ks*32 + lk*8];
                acc = __builtin_amdgcn_mfma_f32_16x16x32_bf16(afr[ks], bfr, acc, 0, 0, 0);
            }
            int n = c*32 + f*16 + lr;
            float cn = cbl[n];
            #pragma unroll
            for (int r = 0; r < 4; ++r) {
                float dist = fmaf(-2.f, acc[r], cn);
                if (dist < bd[r]) { bd[r] = dist; bi[r] = n; }
            }
        }
        __syncthreads();
    }
    #pragma unroll
    for (int r = 0; r < 4; ++r) {
        #pragma unroll
        for (int off = 1; off < 16; off <<= 1) {
            float od = __shfl_xor(bd[r], off, 64);
            int   oi = __shfl_xor(bi[r], off, 64);
            if (od < bd[r] || (od == bd[r] && oi < bi[r])) { bd[r] = od; bi[r] = oi; }
        }
    }
    if (lr == 0) {
        #pragma unroll
        for (int r = 0; r < 4; ++r)
            idx[r0 + w*16 + lk*4 + r] = bi[r];
    }
}

// ---------------- IN-PLACE VQ gather (fused cbam-z multiply; raw z -> bf16 q) ----------------
__global__ __launch_bounds__(256) void vq_gather(
    unsigned short* zq, const float* __restrict__ cb,
    const int* __restrict__ idx, const float* __restrict__ gvec,
    const float* __restrict__ ssm, float* __restrict__ sse, int* __restrict__ counts) {
    __shared__ int hist[KCB];
    for (int i = threadIdx.x; i < KCB; i += 256) hist[i] = 0;
    __syncthreads();
    const unsigned int PB = 256u * HW2;
    float local = 0.f;
    for (int r = blockIdx.x; r < NROWS; r += GATHER_BLOCKS) {
        int id = idx[r];
        if (threadIdx.x == 0) atomicAdd(&hist[id], 1);
        float qv = cb[(size_t)id*256 + threadIdx.x];
        unsigned short* pz = zq + (size_t)r*256 + threadIdx.x;
        unsigned int flat = (unsigned int)r*256u + threadIdx.x;
        unsigned int bb = flat / PB;
        unsigned int rem = flat - bb*PB;
        unsigned int c = rem / (unsigned)HW2;
        unsigned int p = rem - c*(unsigned)HW2;
        float zraw = bf2f(*pz);
        float zv = bf2f(f2bf(zraw*zraw*gvec[bb*256 + c]*ssm[(size_t)bb*HW2 + p]));
        *pz = f2bf(qv);
        float d = qv - zv;
        local = fmaf(d, d, local);
    }
    __shared__ float lds[4];
    for (int off = 32; off; off >>= 1) local += __shfl_down(local, off, 64);
    if ((threadIdx.x & 63) == 0) lds[threadIdx.x >> 6] = local;
    __syncthreads();
    if (threadIdx.x == 0) atomicAdd(sse, lds[0]+lds[1]+lds[2]+lds[3]);
    for (int i = threadIdx.x; i < KCB; i += 256) {
        int h = hist[i];
        if (h) atomicAdd(counts + i, h);
    }
}

// ---------------- loss + perplexity ----------------
__global__ __launch_bounds__(256) void vq_finalize(
    const float* __restrict__ sse, const int* __restrict__ counts,
    float* __restrict__ out) {
    __shared__ float lds[4];
    float h = 0.f;
    for (int n = threadIdx.x; n < KCB; n += 256) {
        float p = (float)counts[n] * (1.f/123008.f);
        h += p * logf(p + 1e-10f);
    }
    for (int off = 32; off; off >>= 1) h += __shfl_down(h, off, 64);
    if ((threadIdx.x & 63) == 0) lds[threadIdx.x >> 6] = h;
    __syncthreads();
    if (threadIdx.x == 0) {
        out[1572864] = 1.25f * sse[0] / 31490048.f;
        out[1572865] = expf(-(lds[0]+lds[1]+lds[2]+lds[3]));
    }
}

// ---------------- dt2 via parity-split MFMA, fused input cbam multiply ----------------
__global__ __launch_bounds__(256) void dt2_mfma(
    const unsigned short* __restrict__ Y, const unsigned short* __restrict__ apack,
    const float* __restrict__ bias, const float* __restrict__ gvec,
    const float* __restrict__ ssm, float* __restrict__ out) {
    __shared__ __align__(16) unsigned short Iraw[2][289*40];
    __shared__ float gs[256];
    int b = blockIdx.y, t = blockIdx.x;
    int a0 = (t >> 2)*16, b0 = (t & 3)*16;
    int p = threadIdx.x >> 6;
    int l = threadIdx.x & 63;
    int lr = l & 15, lk = l >> 4;
    const unsigned short* src = Y + (size_t)b*HW1*256;
    const float* ssb = ssm + (size_t)b*HW1;
    gs[threadIdx.x] = gvec[b*256 + threadIdx.x];
    __syncthreads();

    auto STAGE = [&](int cc, int bufi) {
        #pragma unroll
        for (int pass = 0; pass < 5; ++pass) {
            int u = pass*256 + threadIdx.x;
            if (u < 1156) {
                int sp = u >> 2, q = u & 3;
                int r = (sp*241) >> 12, c = sp - r*17;
                int ia = a0 - 1 + r, ib = b0 - 1 + c;
                short8 v = (short8){0,0,0,0,0,0,0,0};
                bool valid = (ia >= 0) && (ia < 63) && (ib >= 0) && (ib < 63);
                if (valid) {
                    v = *(const short8*)(src + ((size_t)ia*63 + ib)*256 + cc*32 + q*8);
                    float sv = ssb[(size_t)ia*63 + ib];
                    int c0 = cc*32 + q*8;
                    unsigned int pk[4];
                    #pragma unroll
                    for (int j = 0; j < 4; ++j) {
                        float f0 = bf2f((unsigned short)v[2*j]);
                        float f1 = bf2f((unsigned short)v[2*j+1]);
                        f0 = f0*f0*gs[c0+2*j]*sv;
                        f1 = f1*f1*gs[c0+2*j+1]*sv;
                        pk[j] = (unsigned int)f2bf(f0) | ((unsigned int)f2bf(f1) << 16);
                    }
                    v = *(const short8*)pk;
                }
                *(short8*)&Iraw[bufi][sp*40 + q*8] = v;
            }
        }
    };

    f32x4 acc[16];
    #pragma unroll
    for (int i = 0; i < 16; ++i) acc[i] = (f32x4){0.f,0.f,0.f,0.f};

    STAGE(0, 0);
    for (int cc = 0; cc < 8; ++cc) {
        __syncthreads();
        if (cc < 7) STAGE(cc+1, (cc+1)&1);
        const unsigned short* Ib = Iraw[cc & 1];
        #pragma unroll
        for (int j = 0; j < 4; ++j) {
            int jh = j >> 1, jw = j & 1;
            short8 af = *(const short8*)(apack +
                ((size_t)((p*8 + cc)*4 + j))*512 + lr*32 + lk*8);
            int sp0 = (1 - jh)*17 + (lr + 1 - jw);
            #pragma unroll
            for (int nf = 0; nf < 16; ++nf) {
                short8 bf = *(const short8*)&Ib[(sp0 + nf*17)*40 + lk*8];
                acc[nf] = __builtin_amdgcn_mfma_f32_16x16x32_bf16(af, bf, acc[nf], 0, 0, 0);
            }
        }
    }
    if (lk == 0) {
        int kh0 = p >> 1, kw0 = p & 1;
        float bz0 = bias[0], bz1 = bias[1], bz2 = bias[2];
        int wp = 2*(b0 + lr) + kw0;
        #pragma unroll
        for (int nf = 0; nf < 16; ++nf) {
            int h = 2*(a0 + nf) + kh0;
            size_t ob = (size_t)(b*3)*16384 + (size_t)h*128 + wp;
            out[ob]         = acc[nf].x + bz0;
            out[ob + 16384] = acc[nf].y + bz1;
            out[ob + 32768] = acc[nf].z + bz2;
        }
    }
}

// ---------------- launch ----------------
extern "C" void kernel_launch(void* const* d_in, const int* in_sizes, int n_in,
                              void* d_out, int out_size, void* d_ws, size_t ws_size,
                              hipStream_t stream) {
    const float* x      = (const float*)d_in[0];
    const float* ec1_w  = (const float*)d_in[1];
    const float* ec1_b  = (const float*)d_in[2];
    const float* ec2_w  = (const float*)d_in[3];
    const float* ec2_b  = (const float*)d_in[4];
    const float* se1_w1 = (const float*)d_in[5];
    const float* se1_b1 = (const float*)d_in[6];
    const float* se1_w2 = (const float*)d_in[7];
    const float* se1_b2 = (const float*)d_in[8];
    const float* sa1_w  = (const float*)d_in[9];
    const float* se2_w1 = (const float*)d_in[10];
    const float* se2_b1 = (const float*)d_in[11];
    const float* se2_w2 = (const float*)d_in[12];
    const float* se2_b2 = (const float*)d_in[13];
    const float* sa2_w  = (const float*)d_in[14];
    const float* cbk    = (const float*)d_in[15];
    const float* dt1_w  = (const float*)d_in[16];
    const float* dt1_b  = (const float*)d_in[17];
    const float* dt2_w  = (const float*)d_in[18];
    const float* dt2_b  = (const float*)d_in[19];
    const float* dse_w1 = (const float*)d_in[20];
    const float* dse_b1 = (const float*)d_in[21];
    const float* dse_w2 = (const float*)d_in[22];
    const float* dse_b2 = (const float*)d_in[23];
    const float* dsa_w  = (const float*)d_in[24];
    float* out = (float*)d_out;

    unsigned short* Zb = (unsigned short*)d_ws;           // T62 bf16 NCHW z/q (63 MB)
    unsigned short* U0 = Zb + T62;                         // T63 bf16 NHWC (65 MB)
    unsigned short* U1 = U0 + T63;                         // T63 bf16 NHWC (65 MB)
    float* pooled = (float*)(U1 + T63);                    // 32*64*256 floats (2 MB partials)
    float* g      = pooled + 524288;
    float* am     = g + 8192;
    float* ssmap  = am + (size_t)NB*2*HW1;
    float* cbn    = ssmap + (size_t)NB*HW1;
    unsigned short* apackE = (unsigned short*)(cbn + 512);
    unsigned short* apackD = apackE + 262144;
    unsigned short* cbp    = apackD + 262144;
    unsigned short* apackC = cbp + 131072;
    unsigned short* apack2 = apackC + 16384;
    float* sse    = (float*)(apack2 + 65536);
    int*   counts = (int*)(sse + 1);
    int*   idx    = counts + 512;

    // prep
    zero_small<<<1, 256, 0, stream>>>(sse, counts);
    prepack_w<<<1024, 256, 0, stream>>>(ec2_w, apackE, 0);
    prepack_w<<<1024, 256, 0, stream>>>(dt1_w, apackD, 1);
    prepack_c1<<<64, 256, 0, stream>>>(ec1_w, apackC);
    prepack_dt2b<<<256, 256, 0, stream>>>(dt2_w, apack2);
    cb_norm<<<1, 256, 0, stream>>>(cbk, cbn);
    cb_pack<<<512, 256, 0, stream>>>(cbk, cbp);

    // encoder conv1 (MFMA im2col, fused GAP) -> U0 bf16 NHWC; cbam1 stats on U0
    conv1_mfma<<<dim3(64, NB), 256, 0, stream>>>(x, apackC, ec1_b, U0, pooled);
    se_mlp<<<NB, 256, 0, stream>>>(pooled, se1_w1, se1_b1, se1_w2, se1_b2, g, 64);
    chanpool_nhwc<<<dim3(16, NB), 256, 0, stream>>>(U0, g, am, HW1);
    spatial_conv<<<dim3(16, NB), 256, 0, stream>>>(am, sa1_w, ssmap, 63, 63, 0);
    // cbam1 final multiply FUSED into conv2 staging

    // conv2 (U0 -> Zb bf16 NCHW raw-z, fused cbam1 multiply + fused GAP) + cbam2 stats
    convk2_mfma_nhwc<0><<<dim3(64, NB), 256, 0, stream>>>(U0, apackE, ec2_b, g, ssmap, Zb, (unsigned short*)0, pooled, 63, 63, 62, 62, 0);
    se_mlp<<<NB, 256, 0, stream>>>(pooled, se2_w1, se2_b1, se2_w2, se2_b2, g, 64);
    chanpool_z<<<dim3(16, NB), 256, 0, stream>>>(Zb, g, am, HW2);
    spatial_conv<<<dim3(16, NB), 256, 0, stream>>>(am, sa2_w, ssmap, 62, 62, 0);
    // cbam2 final multiply FUSED into vq_assign staging + vq_gather

    // VQ: assign (fused cbam-z) -> gather (fused cbam-z, q in-place) -> NHWC
    vq_assign_mfma<<<NROWS/64, 256, 0, stream>>>(Zb, cbp, cbn, g, ssmap, idx);
    vq_gather<<<GATHER_BLOCKS, 256, 0, stream>>>(Zb, cbk, idx, g, ssmap, sse, counts);
    vq_finalize<<<1, 256, 0, stream>>>(sse, counts, out);
    to_nhwc_bf16<<<dim3(16, NB), 256, 0, stream>>>(Zb, U1, HW2);

    // decoder dt1 (U1 -> U0 bf16 NHWC, fused GAP) + cbam3 stats on U0
    convk2_mfma_nhwc<1><<<dim3(64, NB), 256, 0, stream>>>(U1, apackD, dt1_b, (const float*)0, (const float*)0, (unsigned short*)0, U0, pooled, 62, 62, 63, 63, 1);
    se_mlp<<<NB, 256, 0, stream>>>(pooled, dse_w1, dse_b1, dse_w2, dse_b2, g, 64);
    chanpool_nhwc<<<dim3(16, NB), 256, 0, stream>>>(U0, g, am, HW1);
    spatial_conv<<<dim3(16, NB), 256, 0, stream>>>(am, dsa_w, ssmap, 63, 63, 1);
    // cbam3 final multiply FUSED into dt2 staging

    // final convT (parity-split MFMA, fused cbam3 multiply) -> out
    dt2_mfma<<<dim3(16, NB), 256, 0, stream>>>(U0, apack2, dt2_b, g, ssmap, out);
}

// Round 22
// 714.347 us; speedup vs baseline: 1.0059x; 1.0059x over previous
//
#include <hip/hip_runtime.h>
#include <math.h>

// ---------------- sizes ----------------
#define NB 32
#define HID 256
#define HW1 (63*63)      // 3969
#define HW2 (62*62)      // 3844
#define T63 ((size_t)NB*HID*HW1)   // 32,514,048
#define T62 ((size_t)NB*HID*HW2)   // 31,490,048
#define NROWS 123008               // T62 / 256
#define KCB 512
#define GATHER_BLOCKS 1024

typedef __attribute__((ext_vector_type(8))) short short8;
typedef __attribute__((ext_vector_type(4))) float f32x4;
typedef __attribute__((ext_vector_type(4))) unsigned short us4;

__device__ __forceinline__ unsigned short f2bf(float f) {
    union { float f; unsigned int u; } v; v.f = f;
    unsigned int u = v.u;
    return (unsigned short)((u + 0x7FFFu + ((u >> 16) & 1u)) >> 16);
}
__device__ __forceinline__ float bf2f(unsigned short u) {
    union { unsigned int i; float f; } v; v.i = ((unsigned int)u) << 16;
    return v.f;
}

// ---------------- zero helpers ----------------
__global__ __launch_bounds__(256) void zero_small(float* __restrict__ sse, int* __restrict__ counts) {
    if (threadIdx.x == 0) sse[0] = 0.f;
    for (int i = threadIdx.x; i < KCB; i += 256) counts[i] = 0;
}

// ---------------- conv1 weight prepack ----------------
__global__ __launch_bounds__(256) void prepack_c1(
    const float* __restrict__ w, unsigned short* __restrict__ pack) {
    int t = blockIdx.x*256 + threadIdx.x;
    if (t >= 16384) return;
    int j = t & 7, lk = (t >> 3) & 3, co = (t >> 5) & 255, kc = t >> 13;
    int k = kc*32 + lk*8 + j;
    pack[t] = (k < 48) ? f2bf(w[co*48 + k]) : (unsigned short)0;
}

// ---------------- conv1: 3->256, k4, s2, relu -> bf16 NHWC via im2col MFMA; fused GAP partials ----------------
__global__ __launch_bounds__(256) void conv1_mfma(
    const float* __restrict__ x, const unsigned short* __restrict__ apack,
    const float* __restrict__ bias, unsigned short* __restrict__ X0,
    float* __restrict__ poolp) {
    __shared__ float xs[3][18][18];
    __shared__ __align__(16) unsigned short Bm[64*72];
    int b = blockIdx.y, t = blockIdx.x;
    int oh0 = (t >> 3)*8, ow0 = (t & 7)*8;
    int ih0 = oh0*2, iw0 = ow0*2;
    const float* xb = x + (size_t)b*3*128*128;
    for (int i = threadIdx.x; i < 972; i += 256) {
        int c = i / 324, rem = i - c*324, r = rem / 18, cl = rem - r*18;
        int ih = ih0 + r, iw = iw0 + cl;
        xs[c][r][cl] = (ih < 128 && iw < 128) ? xb[((size_t)c*128 + ih)*128 + iw] : 0.f;
    }
    __syncthreads();
    for (int i = threadIdx.x; i < 2048; i += 256) {
        int px = i >> 5, kp = (i & 31)*2;
        int ph = px >> 3, pw = px & 7;
        unsigned int pk = 0;
        #pragma unroll
        for (int u = 0; u < 2; ++u) {
            int k = kp + u;
            float v = 0.f;
            if (k < 48) {
                int c = k >> 4, k2 = k & 15, kh = k2 >> 2, kw = k2 & 3;
                v = xs[c][ph*2+kh][pw*2+kw];
            }
            pk |= ((unsigned int)f2bf(v)) << (16*u);
        }
        *(unsigned int*)&Bm[px*72 + kp] = pk;
    }
    __syncthreads();

    int w = threadIdx.x >> 6, l = threadIdx.x & 63;
    int lr = l & 15, lk = l >> 4;
    f32x4 acc[4][4];
    #pragma unroll
    for (int i = 0; i < 4; ++i)
        #pragma unroll
        for (int j = 0; j < 4; ++j) acc[i][j] = (f32x4){0.f,0.f,0.f,0.f};

    #pragma unroll
    for (int kc = 0; kc < 2; ++kc) {
        short8 bf[4];
        #pragma unroll
        for (int pxf = 0; pxf < 4; ++pxf)
            bf[pxf] = *(const short8*)&Bm[(pxf*16+lr)*72 + kc*32 + lk*8];
        #pragma unroll
        for (int cof = 0; cof < 4; ++cof) {
            int co = w*64 + cof*16 + lr;
            short8 af = *(const short8*)(apack + (((size_t)kc*256 + co)*4 + (size_t)lk)*8);
            acc[cof][0] = __builtin_amdgcn_mfma_f32_16x16x32_bf16(af, bf[0], acc[cof][0], 0, 0, 0);
            acc[cof][1] = __builtin_amdgcn_mfma_f32_16x16x32_bf16(af, bf[1], acc[cof][1], 0, 0, 0);
            acc[cof][2] = __builtin_amdgcn_mfma_f32_16x16x32_bf16(af, bf[2], acc[cof][2], 0, 0, 0);
            acc[cof][3] = __builtin_amdgcn_mfma_f32_16x16x32_bf16(af, bf[3], acc[cof][3], 0, 0, 0);
        }
    }
    float gsum[4][4];
    #pragma unroll
    for (int i = 0; i < 4; ++i)
        #pragma unroll
        for (int j = 0; j < 4; ++j) gsum[i][j] = 0.f;
    #pragma unroll
    for (int cof = 0; cof < 4; ++cof) {
        int cob = w*64 + cof*16 + lk*4;
        float4 bz = *(const float4*)&bias[cob];
        #pragma unroll
        for (int pxf = 0; pxf < 4; ++pxf) {
            int px = pxf*16 + lr;
            int oh = oh0 + (px >> 3), ow = ow0 + (px & 7);
            if (oh < 63 && ow < 63) {
                f32x4 a = acc[cof][pxf];
                float r0 = fmaxf(a.x + bz.x, 0.f);
                float r1 = fmaxf(a.y + bz.y, 0.f);
                float r2 = fmaxf(a.z + bz.z, 0.f);
                float r3 = fmaxf(a.w + bz.w, 0.f);
                gsum[cof][0] += r0; gsum[cof][1] += r1;
                gsum[cof][2] += r2; gsum[cof][3] += r3;
                us4 pk = { f2bf(r0), f2bf(r1), f2bf(r2), f2bf(r3) };
                *(us4*)(X0 + ((size_t)b*HW1 + (size_t)oh*63 + ow)*256 + cob) = pk;
            }
        }
    }
    #pragma unroll
    for (int cof = 0; cof < 4; ++cof)
        #pragma unroll
        for (int j = 0; j < 4; ++j) {
            #pragma unroll
            for (int m = 1; m < 16; m <<= 1)
                gsum[cof][j] += __shfl_xor(gsum[cof][j], m, 64);
        }
    if (lr == 0) {
        float* dst = poolp + ((size_t)b*64 + blockIdx.x)*256;
        #pragma unroll
        for (int cof = 0; cof < 4; ++cof)
            #pragma unroll
            for (int j = 0; j < 4; ++j)
                dst[w*64 + cof*16 + lk*4 + j] = gsum[cof][j] * (1.f/HW1);
    }
}

// ---------------- SE MLP (sums `parts` partial slices) ----------------
__global__ __launch_bounds__(256) void se_mlp(
    const float* __restrict__ pooled, const float* __restrict__ w1,
    const float* __restrict__ b1, const float* __restrict__ w2,
    const float* __restrict__ b2, float* __restrict__ g, int parts) {
    int b = blockIdx.x;
    __shared__ float ps[256], hs[16];
    float s = 0.f;
    for (int k = 0; k < parts; ++k)
        s += pooled[((size_t)b*parts + k)*256 + threadIdx.x];
    ps[threadIdx.x] = s;
    __syncthreads();
    if (threadIdx.x < 16) {
        float a = b1[threadIdx.x];
        const float* wr = w1 + threadIdx.x*256;
        for (int k = 0; k < 256; ++k) a = fmaf(ps[k], wr[k], a);
        hs[threadIdx.x] = fmaxf(a, 0.f);
    }
    __syncthreads();
    float a = b2[threadIdx.x];
    const float* wr = w2 + threadIdx.x*16;
    #pragma unroll
    for (int j = 0; j < 16; ++j) a = fmaf(hs[j], wr[j], a);
    g[b*256 + threadIdx.x] = 1.f / (1.f + expf(-a));
}

// ---------------- channel mean/max of x*g (NHWC bf16) ----------------
__global__ __launch_bounds__(256) void chanpool_nhwc(
    const unsigned short* __restrict__ X, const float* __restrict__ g,
    float* __restrict__ am, int HW) {
    int b = blockIdx.y;
    __shared__ float gs[256];
    gs[threadIdx.x] = g[b*256 + threadIdx.x];
    __syncthreads();
    int p = blockIdx.x*256 + threadIdx.x;
    if (p >= HW) return;
    const unsigned short* xp = X + ((size_t)b*HW + p)*256;
    float s = 0.f, mx = -3.0e38f;
    for (int o = 0; o < 32; ++o) {
        short8 v = *(const short8*)(xp + o*8);
        #pragma unroll
        for (int j = 0; j < 8; ++j) {
            float f = bf2f((unsigned short)v[j]) * gs[o*8+j];
            s += f; mx = fmaxf(mx, f);
        }
    }
    am[((size_t)b*2)*HW + p]   = s * (1.f/256.f);
    am[((size_t)b*2+1)*HW + p] = mx;
}

// ---------------- channel mean/max of x*g (bf16 NCHW, encoder-2 z) ----------------
__global__ __launch_bounds__(256) void chanpool_z(
    const unsigned short* __restrict__ Z, const float* __restrict__ g,
    float* __restrict__ am, int HW) {
    int b = blockIdx.y;
    __shared__ float gs[256];
    gs[threadIdx.x] = g[b*256 + threadIdx.x];
    __syncthreads();
    int p = blockIdx.x*256 + threadIdx.x;
    if (p >= HW) return;
    const unsigned short* xb = Z + (size_t)b*256*HW + p;
    float s = 0.f, mx = -3.0e38f;
    for (int c = 0; c < 256; ++c) {
        float v = bf2f(xb[(size_t)c*HW]) * gs[c];
        s += v; mx = fmaxf(mx, v);
    }
    am[((size_t)b*2)*HW + p]   = s * (1.f/256.f);
    am[((size_t)b*2+1)*HW + p] = mx;
}

// ---------------- 7x7 spatial conv on [mean,max], sigmoid ----------------
__global__ __launch_bounds__(256) void spatial_conv(
    const float* __restrict__ am, const float* __restrict__ sw,
    float* __restrict__ ss, int H, int W, int transpose) {
    int b = blockIdx.y;
    int p = blockIdx.x*256 + threadIdx.x;
    __shared__ float ws[98];
    if (threadIdx.x < 98) {
        int c = threadIdx.x / 49, k = threadIdx.x % 49;
        int kh = k / 7, kw = k % 7;
        ws[threadIdx.x] = transpose ? sw[c*49 + (6-kh)*7 + (6-kw)]
                                    : sw[c*49 + kh*7 + kw];
    }
    __syncthreads();
    if (p >= H*W) return;
    int oh = p / W, ow = p % W;
    float acc = 0.f;
    #pragma unroll
    for (int c = 0; c < 2; ++c) {
        const float* ab = am + ((size_t)b*2 + c)*H*W;
        for (int kh = 0; kh < 7; ++kh) {
            int ih = oh + kh - 3;
            if (ih < 0 || ih >= H) continue;
            for (int kw = 0; kw < 7; ++kw) {
                int iw = ow + kw - 3;
                if (iw < 0 || iw >= W) continue;
                acc = fmaf(ab[(size_t)ih*W + iw], ws[c*49 + kh*7 + kw], acc);
            }
        }
    }
    ss[(size_t)b*H*W + p] = 1.f / (1.f + expf(-acc));
}

// ---------------- IN-PLACE bf16 NCHW: z = z*z*g*sig(s) (encoder-2) ----------------
__global__ __launch_bounds__(256) void cbam_z(
    unsigned short* Z, const float* __restrict__ g,
    const float* __restrict__ ss, int HW) {
    int b = blockIdx.y;
    int e2 = blockIdx.x*256 + threadIdx.x;
    if (e2 >= 128*HW) return;
    size_t e = (size_t)e2*2;
    int c = (int)(e / HW), p = (int)(e % HW);
    float gc = g[b*256 + c];
    float s0 = ss[(size_t)b*HW + p];
    float s1 = ss[(size_t)b*HW + p + 1];
    unsigned int* px = (unsigned int*)(Z + (size_t)b*256*HW + e);
    unsigned int v = *px;
    float f0 = bf2f((unsigned short)(v & 0xffff));
    float f1 = bf2f((unsigned short)(v >> 16));
    f0 = f0*f0*gc*s0;
    f1 = f1*f1*gc*s1;
    *px = (unsigned int)f2bf(f0) | ((unsigned int)f2bf(f1) << 16);
}

// ---------------- bf16 NCHW -> NHWC bf16 (q after VQ) ----------------
__global__ __launch_bounds__(256) void to_nhwc_bf16(
    const unsigned short* __restrict__ Z, unsigned short* __restrict__ X, int HW) {
    int b = blockIdx.y;
    int p = blockIdx.x*256 + threadIdx.x;
    bool valid = p < HW;
    const unsigned short* inb = Z + (size_t)b*256*HW + p;
    unsigned short* dst = X + ((size_t)b*HW + p)*256;
    #pragma unroll
    for (int ch = 0; ch < 4; ++ch) {
        unsigned short buf[64];
        #pragma unroll
        for (int j = 0; j < 64; ++j)
            buf[j] = valid ? inb[(size_t)(ch*64 + j)*HW] : (unsigned short)0;
        if (valid) {
            #pragma unroll
            for (int j2 = 0; j2 < 8; ++j2)
                *(short8*)(dst + ch*64 + j2*8) = *(const short8*)&buf[j2*8];
        }
    }
}

// ---------------- weight prepack into MFMA-fragment layout (bf16) ----------------
__global__ __launch_bounds__(256) void prepack_w(
    const float* __restrict__ w, unsigned short* __restrict__ pack, int transpose_flip) {
    int t = blockIdx.x*256 + threadIdx.x;
    int j = t & 7, koct = (t >> 3) & 3, co = (t >> 5) & 255, tap = (t >> 13) & 3, cc = t >> 15;
    int ci = cc*32 + koct*8 + j;
    int kh = tap >> 1, kw = tap & 1;
    float v;
    if (transpose_flip) v = w[((size_t)ci*256 + co)*4 + (1-kh)*2 + (1-kw)];
    else                v = w[((size_t)co*256 + ci)*4 + kh*2 + kw];
    pack[t] = f2bf(v);
}

// ---------------- dt2 weight prepack (MFMA A-frag) ----------------
__global__ __launch_bounds__(256) void prepack_dt2b(
    const float* __restrict__ w, unsigned short* __restrict__ pk) {
    int t = blockIdx.x*256 + threadIdx.x;
    int jj = t & 7, lk = (t >> 3) & 3, co = (t >> 5) & 15, j = (t >> 9) & 3, cc = (t >> 11) & 7, p = t >> 14;
    int ci = cc*32 + lk*8 + jj;
    int kh0 = p >> 1, kw0 = p & 1;
    const int dj[4] = {0, 2, 8, 10};
    float v = 0.f;
    if (co < 3) v = w[(size_t)ci*48 + co*16 + kh0*4 + kw0 + dj[j]];
    pk[t] = f2bf(v);
}

// ---------------- MFMA conv k=2 s=1, NHWC bf16 input, 4x16 tiles, BK=64, XCD swizzle; fused GAP ----------------
// MODE 0: fused input cbam multiply (x*x*g*ss), bf16 NCHW out (conv2 -> z).
// MODE 1: plain input, bf16 NHWC out via LDS-staged epilogue (dt1).
template <int MODE>
__global__ __launch_bounds__(256) void convk2_mfma_nhwc(
    const unsigned short* __restrict__ Xin, const unsigned short* __restrict__ apack,
    const float* __restrict__ bias, const float* __restrict__ gvec,
    const float* __restrict__ ssm, unsigned short* __restrict__ outZ,
    unsigned short* __restrict__ outU,
    float* __restrict__ poolp,
    int inH, int inW, int outH, int outW, int pad) {
    __shared__ __align__(16) unsigned short Sh[MODE ? 16896 : 13600];
    __shared__ float gs[256];
    unsigned short* Ir0 = Sh;
    unsigned short* Ir1 = Sh + 6800;
    int b = blockIdx.y;
    int raw = blockIdx.x;
    int xcd = raw & 7, jj = raw >> 3;
    int t = (xcd + 8*(jj >> 2))*4 + (jj & 3);
    int oh0 = (t >> 2) * 4, ow0 = (t & 3) * 16;
    int w = threadIdx.x >> 6, l = threadIdx.x & 63;
    int lr = l & 15, lk = l >> 4;
    const unsigned short* src = Xin + (size_t)b*inH*inW*256;
    const float* ssb = (MODE == 0) ? (ssm + (size_t)b*inH*inW) : (const float*)0;
    if (MODE == 0) {
        gs[threadIdx.x] = gvec[b*256 + threadIdx.x];
        __syncthreads();
    }

    f32x4 acc[4][4];
    #pragma unroll
    for (int i = 0; i < 4; ++i)
        #pragma unroll
        for (int j = 0; j < 4; ++j) acc[i][j] = (f32x4){0.f,0.f,0.f,0.f};

    auto STAGE = [&](int cc, int bufi) {
        unsigned short* Ib = bufi ? Ir1 : Ir0;
        #pragma unroll
        for (int pass = 0; pass < 3; ++pass) {
            int u = pass*256 + threadIdx.x;
            if (u < 680) {
                int sub = (u >= 340) ? 1 : 0;
                int uu = u - sub*340;
                int sp = uu >> 2, q = uu & 3;
                int r = (sp*241) >> 12, c = sp - r*17;
                int gh = oh0 + r - pad, gw = ow0 + c - pad;
                short8 v = (short8){0,0,0,0,0,0,0,0};
                bool valid = (gh >= 0) && (gh < inH) && (gw >= 0) && (gw < inW);
                if (valid)
                    v = *(const short8*)(src + ((size_t)gh*inW + gw)*256 + (cc+sub)*32 + q*8);
                if (MODE == 0) {
                    if (valid) {
                        float sv = ssb[(size_t)gh*inW + gw];
                        int c0 = (cc+sub)*32 + q*8;
                        unsigned int pk[4];
                        #pragma unroll
                        for (int j = 0; j < 4; ++j) {
                            float f0 = bf2f((unsigned short)v[2*j]);
                            float f1 = bf2f((unsigned short)v[2*j+1]);
                            f0 = f0*f0*gs[c0+2*j]*sv;
                            f1 = f1*f1*gs[c0+2*j+1]*sv;
                            pk[j] = (unsigned int)f2bf(f0) | ((unsigned int)f2bf(f1) << 16);
                        }
                        v = *(const short8*)pk;
                    }
                }
                *(short8*)&Ib[sub*3400 + sp*40 + q*8] = v;
            }
        }
    };

    STAGE(0, 0);
    for (int cc = 0; cc < 8; cc += 2) {
        __syncthreads();
        if (cc < 6) STAGE(cc+2, ((cc >> 1) + 1) & 1);
        const unsigned short* Ibase = ((cc >> 1) & 1) ? Ir1 : Ir0;
        #pragma unroll
        for (int half = 0; half < 2; ++half) {
            const unsigned short* Ib = Ibase + half*3400;
            #pragma unroll
            for (int tap = 0; tap < 4; ++tap) {
                int kh = tap >> 1, kw = tap & 1;
                int spb = kh*17 + kw + lr;
                short8 b0 = *(const short8*)&Ib[(spb     )*40 + lk*8];
                short8 b1 = *(const short8*)&Ib[(spb + 17)*40 + lk*8];
                short8 b2 = *(const short8*)&Ib[(spb + 34)*40 + lk*8];
                short8 b3 = *(const short8*)&Ib[(spb + 51)*40 + lk*8];
                const unsigned short* abase = apack + (((size_t)((cc+half)*4 + tap)*256)*4 + (size_t)lk)*8;
                #pragma unroll
                for (int cof = 0; cof < 4; ++cof) {
                    int co = w*64 + cof*16 + lr;
                    short8 af = *(const short8*)(abase + (size_t)co*32);
                    acc[cof][0] = __builtin_amdgcn_mfma_f32_16x16x32_bf16(af, b0, acc[cof][0], 0, 0, 0);
                    acc[cof][1] = __builtin_amdgcn_mfma_f32_16x16x32_bf16(af, b1, acc[cof][1], 0, 0, 0);
                    acc[cof][2] = __builtin_amdgcn_mfma_f32_16x16x32_bf16(af, b2, acc[cof][2], 0, 0, 0);
                    acc[cof][3] = __builtin_amdgcn_mfma_f32_16x16x32_bf16(af, b3, acc[cof][3], 0, 0, 0);
                }
            }
        }
    }
    float gsum[4][4];
    #pragma unroll
    for (int i = 0; i < 4; ++i)
        #pragma unroll
        for (int j = 0; j < 4; ++j) gsum[i][j] = 0.f;
    int ow = ow0 + lr;
    if (MODE == 0) {
        #pragma unroll
        for (int cof = 0; cof < 4; ++cof) {
            int cob = w*64 + cof*16 + lk*4;
            float4 bz = *(const float4*)&bias[cob];
            #pragma unroll
            for (int pxf = 0; pxf < 4; ++pxf) {
                int oh = oh0 + pxf;
                if (oh < outH && ow < outW) {
                    f32x4 a = acc[cof][pxf];
                    float r0 = fmaxf(a.x + bz.x, 0.f);
                    float r1 = fmaxf(a.y + bz.y, 0.f);
                    float r2 = fmaxf(a.z + bz.z, 0.f);
                    float r3 = fmaxf(a.w + bz.w, 0.f);
                    gsum[cof][0] += r0; gsum[cof][1] += r1;
                    gsum[cof][2] += r2; gsum[cof][3] += r3;
                    size_t base = ((size_t)(b*256 + cob)*outH + oh)*outW + ow;
                    size_t st = (size_t)outH*outW;
                    outZ[base]        = f2bf(r0);
                    outZ[base +   st] = f2bf(r1);
                    outZ[base + 2*st] = f2bf(r2);
                    outZ[base + 3*st] = f2bf(r3);
                }
            }
        }
    } else {
        __syncthreads();
        #pragma unroll
        for (int cof = 0; cof < 4; ++cof) {
            int cob = w*64 + cof*16 + lk*4;
            float4 bz = *(const float4*)&bias[cob];
            #pragma unroll
            for (int pxf = 0; pxf < 4; ++pxf) {
                f32x4 a = acc[cof][pxf];
                float r0 = fmaxf(a.x + bz.x, 0.f);
                float r1 = fmaxf(a.y + bz.y, 0.f);
                float r2 = fmaxf(a.z + bz.z, 0.f);
                float r3 = fmaxf(a.w + bz.w, 0.f);
                int oh = oh0 + pxf;
                if (oh < outH && ow < outW) {
                    gsum[cof][0] += r0; gsum[cof][1] += r1;
                    gsum[cof][2] += r2; gsum[cof][3] += r3;
                }
                us4 pk = { f2bf(r0), f2bf(r1), f2bf(r2), f2bf(r3) };
                *(us4*)&Sh[(pxf*16 + lr)*264 + cob] = pk;
            }
        }
        __syncthreads();
        int owp = threadIdx.x >> 4, c0 = (threadIdx.x & 15)*16;
        int oww = ow0 + owp;
        #pragma unroll
        for (int row = 0; row < 4; ++row) {
            int oh = oh0 + row;
            if (oh < outH && oww < outW) {
                unsigned short* dst = outU + (((size_t)b*outH + oh)*outW + oww)*256 + c0;
                *(short8*)dst       = *(const short8*)&Sh[(row*16 + owp)*264 + c0];
                *(short8*)(dst + 8) = *(const short8*)&Sh[(row*16 + owp)*264 + c0 + 8];
            }
        }
    }
    #pragma unroll
    for (int cof = 0; cof < 4; ++cof)
        #pragma unroll
        for (int j = 0; j < 4; ++j) {
            #pragma unroll
            for (int m = 1; m < 16; m <<= 1)
                gsum[cof][j] += __shfl_xor(gsum[cof][j], m, 64);
        }
    if (lr == 0) {
        float inv = 1.f / (float)(outH * outW);
        float* dst = poolp + ((size_t)b*64 + raw)*256;
        #pragma unroll
        for (int cof = 0; cof < 4; ++cof)
            #pragma unroll
            for (int j = 0; j < 4; ++j)
                dst[w*64 + cof*16 + lk*4 + j] = gsum[cof][j] * inv;
    }
}

// ---------------- codebook norms ----------------
__global__ __launch_bounds__(256) void cb_norm(
    const float* __restrict__ cb, float* __restrict__ cbn) {
    for (int n = threadIdx.x; n < KCB; n += 256) {
        float s = 0.f;
        for (int k = 0; k < 256; ++k) { float v = cb[(size_t)n*256+k]; s = fmaf(v,v,s); }
        cbn[n] = s;
    }
}

// ---------------- codebook bf16 pack ----------------
__global__ __launch_bounds__(256) void cb_pack(
    const float* __restrict__ cb, unsigned short* __restrict__ cbp) {
    int t = blockIdx.x*256 + threadIdx.x;
    cbp[t] = f2bf(cb[t]);
}

// ---------------- MFMA VQ assign: bf16 z, LDS-staged codebook, 64 rows/block ----------------
__global__ __launch_bounds__(256) void vq_assign_mfma(
    const unsigned short* __restrict__ z, const unsigned short* __restrict__ cbp,
    const float* __restrict__ cbn, int* __restrict__ idx) {
    __shared__ __align__(16) unsigned short zb[64*264];
    __shared__ __align__(16) unsigned short cbs[2][32*264];
    __shared__ float cbl[KCB];
    int r0 = blockIdx.x * 64;
    for (int v = threadIdx.x; v < 2048; v += 256) {
        int row = v >> 5, o = v & 31;
        *(short8*)&zb[row*264 + o*8] = *(const short8*)&z[(size_t)(r0+row)*256 + o*8];
    }
    for (int i = threadIdx.x; i < KCB; i += 256) cbl[i] = cbn[i];
    int tcode = threadIdx.x >> 3, tk = threadIdx.x & 7;
    auto STAGE_CB = [&](int c, int bufi) {
        const unsigned short* src = cbp + ((size_t)(c*32 + tcode))*256 + tk*8;
        unsigned short* dst = &cbs[bufi][tcode*264 + tk*8];
        #pragma unroll
        for (int j = 0; j < 4; ++j)
            *(short8*)(dst + j*64) = *(const short8*)(src + j*64);
    };
    STAGE_CB(0, 0);
    __syncthreads();

    int w = threadIdx.x >> 6, l = threadIdx.x & 63;
    int lr = l & 15, lk = l >> 4;
    short8 afr[8];
    #pragma unroll
    for (int ks = 0; ks < 8; ++ks)
        afr[ks] = *(const short8*)&zb[(w*16 + lr)*264 + ks*32 + lk*8];

    float bd[4]; int bi[4];
    #pragma unroll
    for (int r = 0; r < 4; ++r) { bd[r] = 3.0e38f; bi[r] = 0; }

    for (int c = 0; c < 16; ++c) {
        if (c < 15) STAGE_CB(c+1, (c+1)&1);
        const unsigned short* Cb = cbs[c & 1];
        #pragma unroll
        for (int f = 0; f < 2; ++f) {
            f32x4 acc = (f32x4){0.f,0.f,0.f,0.f};
            #pragma unroll
            for (int ks = 0; ks < 8; ++ks) {
                short8 bfr = *(const short8*)&Cb[(f*16 + lr)*264 + ks*32 + lk*8];
                acc = __builtin_amdgcn_mfma_f32_16x16x32_bf16(afr[ks], bfr, acc, 0, 0, 0);
            }
            int n = c*32 + f*16 + lr;
            float cn = cbl[n];
            #pragma unroll
            for (int r = 0; r < 4; ++r) {
                float dist = fmaf(-2.f, acc[r], cn);
                if (dist < bd[r]) { bd[r] = dist; bi[r] = n; }
            }
        }
        __syncthreads();
    }
    #pragma unroll
    for (int r = 0; r < 4; ++r) {
        #pragma unroll
        for (int off = 1; off < 16; off <<= 1) {
            float od = __shfl_xor(bd[r], off, 64);
            int   oi = __shfl_xor(bi[r], off, 64);
            if (od < bd[r] || (od == bd[r] && oi < bi[r])) { bd[r] = od; bi[r] = oi; }
        }
    }
    if (lr == 0) {
        #pragma unroll
        for (int r = 0; r < 4; ++r)
            idx[r0 + w*16 + lk*4 + r] = bi[r];
    }
}

// ---------------- IN-PLACE VQ gather (bf16 z -> bf16 q) ----------------
__global__ __launch_bounds__(256) void vq_gather(
    unsigned short* zq, const float* __restrict__ cb,
    const int* __restrict__ idx, float* __restrict__ sse, int* __restrict__ counts) {
    __shared__ int hist[KCB];
    for (int i = threadIdx.x; i < KCB; i += 256) hist[i] = 0;
    __syncthreads();
    float local = 0.f;
    for (int r = blockIdx.x; r < NROWS; r += GATHER_BLOCKS) {
        int id = idx[r];
        if (threadIdx.x == 0) atomicAdd(&hist[id], 1);
        float qv = cb[(size_t)id*256 + threadIdx.x];
        unsigned short* pz = zq + (size_t)r*256 + threadIdx.x;
        float zv = bf2f(*pz);
        *pz = f2bf(qv);
        float d = qv - zv;
        local = fmaf(d, d, local);
    }
    __shared__ float lds[4];
    for (int off = 32; off; off >>= 1) local += __shfl_down(local, off, 64);
    if ((threadIdx.x & 63) == 0) lds[threadIdx.x >> 6] = local;
    __syncthreads();
    if (threadIdx.x == 0) atomicAdd(sse, lds[0]+lds[1]+lds[2]+lds[3]);
    for (int i = threadIdx.x; i < KCB; i += 256) {
        int h = hist[i];
        if (h) atomicAdd(counts + i, h);
    }
}

// ---------------- loss + perplexity ----------------
__global__ __launch_bounds__(256) void vq_finalize(
    const float* __restrict__ sse, const int* __restrict__ counts,
    float* __restrict__ out) {
    __shared__ float lds[4];
    float h = 0.f;
    for (int n = threadIdx.x; n < KCB; n += 256) {
        float p = (float)counts[n] * (1.f/123008.f);
        h += p * logf(p + 1e-10f);
    }
    for (int off = 32; off; off >>= 1) h += __shfl_down(h, off, 64);
    if ((threadIdx.x & 63) == 0) lds[threadIdx.x >> 6] = h;
    __syncthreads();
    if (threadIdx.x == 0) {
        out[1572864] = 1.25f * sse[0] / 31490048.f;
        out[1572865] = expf(-(lds[0]+lds[1]+lds[2]+lds[3]));
    }
}

// ---------------- dt2 via parity-split MFMA, fused input cbam multiply ----------------
__global__ __launch_bounds__(256) void dt2_mfma(
    const unsigned short* __restrict__ Y, const unsigned short* __restrict__ apack,
    const float* __restrict__ bias, const float* __restrict__ gvec,
    const float* __restrict__ ssm, float* __restrict__ out) {
    __shared__ __align__(16) unsigned short Iraw[2][289*40];
    __shared__ float gs[256];
    int b = blockIdx.y, t = blockIdx.x;
    int a0 = (t >> 2)*16, b0 = (t & 3)*16;
    int p = threadIdx.x >> 6;
    int l = threadIdx.x & 63;
    int lr = l & 15, lk = l >> 4;
    const unsigned short* src = Y + (size_t)b*HW1*256;
    const float* ssb = ssm + (size_t)b*HW1;
    gs[threadIdx.x] = gvec[b*256 + threadIdx.x];
    __syncthreads();

    auto STAGE = [&](int cc, int bufi) {
        #pragma unroll
        for (int pass = 0; pass < 5; ++pass) {
            int u = pass*256 + threadIdx.x;
            if (u < 1156) {
                int sp = u >> 2, q = u & 3;
                int r = (sp*241) >> 12, c = sp - r*17;
                int ia = a0 - 1 + r, ib = b0 - 1 + c;
                short8 v = (short8){0,0,0,0,0,0,0,0};
                bool valid = (ia >= 0) && (ia < 63) && (ib >= 0) && (ib < 63);
                if (valid) {
                    v = *(const short8*)(src + ((size_t)ia*63 + ib)*256 + cc*32 + q*8);
                    float sv = ssb[(size_t)ia*63 + ib];
                    int c0 = cc*32 + q*8;
                    unsigned int pk[4];
                    #pragma unroll
                    for (int j = 0; j < 4; ++j) {
                        float f0 = bf2f((unsigned short)v[2*j]);
                        float f1 = bf2f((unsigned short)v[2*j+1]);
                        f0 = f0*f0*gs[c0+2*j]*sv;
                        f1 = f1*f1*gs[c0+2*j+1]*sv;
                        pk[j] = (unsigned int)f2bf(f0) | ((unsigned int)f2bf(f1) << 16);
                    }
                    v = *(const short8*)pk;
                }
                *(short8*)&Iraw[bufi][sp*40 + q*8] = v;
            }
        }
    };

    f32x4 acc[16];
    #pragma unroll
    for (int i = 0; i < 16; ++i) acc[i] = (f32x4){0.f,0.f,0.f,0.f};

    STAGE(0, 0);
    for (int cc = 0; cc < 8; ++cc) {
        __syncthreads();
        if (cc < 7) STAGE(cc+1, (cc+1)&1);
        const unsigned short* Ib = Iraw[cc & 1];
        #pragma unroll
        for (int j = 0; j < 4; ++j) {
            int jh = j >> 1, jw = j & 1;
            short8 af = *(const short8*)(apack +
                ((size_t)((p*8 + cc)*4 + j))*512 + lr*32 + lk*8);
            int sp0 = (1 - jh)*17 + (lr + 1 - jw);
            #pragma unroll
            for (int nf = 0; nf < 16; ++nf) {
                short8 bf = *(const short8*)&Ib[(sp0 + nf*17)*40 + lk*8];
                acc[nf] = __builtin_amdgcn_mfma_f32_16x16x32_bf16(af, bf, acc[nf], 0, 0, 0);
            }
        }
    }
    if (lk == 0) {
        int kh0 = p >> 1, kw0 = p & 1;
        float bz0 = bias[0], bz1 = bias[1], bz2 = bias[2];
        int wp = 2*(b0 + lr) + kw0;
        #pragma unroll
        for (int nf = 0; nf < 16; ++nf) {
            int h = 2*(a0 + nf) + kh0;
            size_t ob = (size_t)(b*3)*16384 + (size_t)h*128 + wp;
            out[ob]         = acc[nf].x + bz0;
            out[ob + 16384] = acc[nf].y + bz1;
            out[ob + 32768] = acc[nf].z + bz2;
        }
    }
}

// ---------------- launch ----------------
extern "C" void kernel_launch(void* const* d_in, const int* in_sizes, int n_in,
                              void* d_out, int out_size, void* d_ws, size_t ws_size,
                              hipStream_t stream) {
    const float* x      = (const float*)d_in[0];
    const float* ec1_w  = (const float*)d_in[1];
    const float* ec1_b  = (const float*)d_in[2];
    const float* ec2_w  = (const float*)d_in[3];
    const float* ec2_b  = (const float*)d_in[4];
    const float* se1_w1 = (const float*)d_in[5];
    const float* se1_b1 = (const float*)d_in[6];
    const float* se1_w2 = (const float*)d_in[7];
    const float* se1_b2 = (const float*)d_in[8];
    const float* sa1_w  = (const float*)d_in[9];
    const float* se2_w1 = (const float*)d_in[10];
    const float* se2_b1 = (const float*)d_in[11];
    const float* se2_w2 = (const float*)d_in[12];
    const float* se2_b2 = (const float*)d_in[13];
    const float* sa2_w  = (const float*)d_in[14];
    const float* cbk    = (const float*)d_in[15];
    const float* dt1_w  = (const float*)d_in[16];
    const float* dt1_b  = (const float*)d_in[17];
    const float* dt2_w  = (const float*)d_in[18];
    const float* dt2_b  = (const float*)d_in[19];
    const float* dse_w1 = (const float*)d_in[20];
    const float* dse_b1 = (const float*)d_in[21];
    const float* dse_w2 = (const float*)d_in[22];
    const float* dse_b2 = (const float*)d_in[23];
    const float* dsa_w  = (const float*)d_in[24];
    float* out = (float*)d_out;

    unsigned short* Zb = (unsigned short*)d_ws;           // T62 bf16 NCHW z/q (63 MB)
    unsigned short* U0 = Zb + T62;                         // T63 bf16 NHWC (65 MB)
    unsigned short* U1 = U0 + T63;                         // T63 bf16 NHWC (65 MB)
    float* pooled = (float*)(U1 + T63);                    // 32*64*256 floats (2 MB partials)
    float* g      = pooled + 524288;
    float* am     = g + 8192;
    float* ssmap  = am + (size_t)NB*2*HW1;
    float* cbn    = ssmap + (size_t)NB*HW1;
    unsigned short* apackE = (unsigned short*)(cbn + 512);
    unsigned short* apackD = apackE + 262144;
    unsigned short* cbp    = apackD + 262144;
    unsigned short* apackC = cbp + 131072;
    unsigned short* apack2 = apackC + 16384;
    float* sse    = (float*)(apack2 + 65536);
    int*   counts = (int*)(sse + 1);
    int*   idx    = counts + 512;

    // prep
    zero_small<<<1, 256, 0, stream>>>(sse, counts);
    prepack_w<<<1024, 256, 0, stream>>>(ec2_w, apackE, 0);
    prepack_w<<<1024, 256, 0, stream>>>(dt1_w, apackD, 1);
    prepack_c1<<<64, 256, 0, stream>>>(ec1_w, apackC);
    prepack_dt2b<<<256, 256, 0, stream>>>(dt2_w, apack2);
    cb_norm<<<1, 256, 0, stream>>>(cbk, cbn);
    cb_pack<<<512, 256, 0, stream>>>(cbk, cbp);

    // encoder conv1 (MFMA im2col, fused GAP) -> U0 bf16 NHWC; cbam1 stats on U0
    conv1_mfma<<<dim3(64, NB), 256, 0, stream>>>(x, apackC, ec1_b, U0, pooled);
    se_mlp<<<NB, 256, 0, stream>>>(pooled, se1_w1, se1_b1, se1_w2, se1_b2, g, 64);
    chanpool_nhwc<<<dim3(16, NB), 256, 0, stream>>>(U0, g, am, HW1);
    spatial_conv<<<dim3(16, NB), 256, 0, stream>>>(am, sa1_w, ssmap, 63, 63, 0);
    // cbam1 final multiply FUSED into conv2 staging

    // conv2 (U0 -> Zb bf16 NCHW, fused cbam1 multiply + fused GAP) + cbam2 stats => z in Zb
    convk2_mfma_nhwc<0><<<dim3(64, NB), 256, 0, stream>>>(U0, apackE, ec2_b, g, ssmap, Zb, (unsigned short*)0, pooled, 63, 63, 62, 62, 0);
    se_mlp<<<NB, 256, 0, stream>>>(pooled, se2_w1, se2_b1, se2_w2, se2_b2, g, 64);
    chanpool_z<<<dim3(16, NB), 256, 0, stream>>>(Zb, g, am, HW2);
    spatial_conv<<<dim3(16, NB), 256, 0, stream>>>(am, sa2_w, ssmap, 62, 62, 0);
    cbam_z<<<dim3(1922, NB), 256, 0, stream>>>(Zb, g, ssmap, HW2);

    // VQ: z in Zb -> q in Zb (in-place bf16), then q -> U1 bf16 NHWC
    vq_assign_mfma<<<NROWS/64, 256, 0, stream>>>(Zb, cbp, cbn, idx);
    vq_gather<<<GATHER_BLOCKS, 256, 0, stream>>>(Zb, cbk, idx, sse, counts);
    vq_finalize<<<1, 256, 0, stream>>>(sse, counts, out);
    to_nhwc_bf16<<<dim3(16, NB), 256, 0, stream>>>(Zb, U1, HW2);

    // decoder dt1 (U1 -> U0 bf16 NHWC, fused GAP) + cbam3 stats on U0
    convk2_mfma_nhwc<1><<<dim3(64, NB), 256, 0, stream>>>(U1, apackD, dt1_b, (const float*)0, (const float*)0, (unsigned short*)0, U0, pooled, 62, 62, 63, 63, 1);
    se_mlp<<<NB, 256, 0, stream>>>(pooled, dse_w1, dse_b1, dse_w2, dse_b2, g, 64);
    chanpool_nhwc<<<dim3(16, NB), 256, 0, stream>>>(U0, g, am, HW1);
    spatial_conv<<<dim3(16, NB), 256, 0, stream>>>(am, dsa_w, ssmap, 63, 63, 1);
    // cbam3 final multiply FUSED into dt2 staging

    // final convT (parity-split MFMA, fused cbam3 multiply) -> out
    dt2_mfma<<<dim3(16, NB), 256, 0, stream>>>(U0, apack2, dt2_b, g, ssmap, out);
}

// Round 23
// 701.641 us; speedup vs baseline: 1.0241x; 1.0181x over previous
//
#include <hip/hip_runtime.h>
#include <math.h>

// ---------------- sizes ----------------
#define NB 32
#define HID 256
#define HW1 (63*63)      // 3969
#define HW2 (62*62)      // 3844
#define T63 ((size_t)NB*HID*HW1)   // 32,514,048
#define T62 ((size_t)NB*HID*HW2)   // 31,490,048
#define NROWS 123008               // T62 / 256
#define KCB 512
#define GATHER_BLOCKS 1024

typedef __attribute__((ext_vector_type(8))) short short8;
typedef __attribute__((ext_vector_type(4))) float f32x4;
typedef __attribute__((ext_vector_type(4))) unsigned short us4;

__device__ __forceinline__ unsigned short f2bf(float f) {
    union { float f; unsigned int u; } v; v.f = f;
    unsigned int u = v.u;
    return (unsigned short)((u + 0x7FFFu + ((u >> 16) & 1u)) >> 16);
}
__device__ __forceinline__ float bf2f(unsigned short u) {
    union { unsigned int i; float f; } v; v.i = ((unsigned int)u) << 16;
    return v.f;
}

// ---------------- fused prep: all weight prepacks + codebook pack/norm + zeroing ----------------
__global__ __launch_bounds__(256) void prep_all(
    const float* __restrict__ ec2_w, unsigned short* __restrict__ apackE,
    const float* __restrict__ dt1_w, unsigned short* __restrict__ apackD,
    const float* __restrict__ ec1_w, unsigned short* __restrict__ apackC,
    const float* __restrict__ dt2_w, unsigned short* __restrict__ apack2,
    const float* __restrict__ cb, unsigned short* __restrict__ cbp,
    float* __restrict__ cbn, float* __restrict__ sse, int* __restrict__ counts) {
    int blk = blockIdx.x;
    if (blk < 2048) {
        // prepack_w for conv2 (flip=0) and dt1 (flip=1)
        int flip = blk >> 10;
        const float* w = flip ? dt1_w : ec2_w;
        unsigned short* pack = flip ? apackD : apackE;
        int t = (blk & 1023)*256 + threadIdx.x;
        int j = t & 7, koct = (t >> 3) & 3, co = (t >> 5) & 255, tap = (t >> 13) & 3, cc = t >> 15;
        int ci = cc*32 + koct*8 + j;
        int kh = tap >> 1, kw = tap & 1;
        float v;
        if (flip) v = w[((size_t)ci*256 + co)*4 + (1-kh)*2 + (1-kw)];
        else      v = w[((size_t)co*256 + ci)*4 + kh*2 + kw];
        pack[t] = f2bf(v);
    } else if (blk < 2112) {
        // prepack_c1
        int t = (blk - 2048)*256 + threadIdx.x;
        int j = t & 7, lk = (t >> 3) & 3, co = (t >> 5) & 255, kc = t >> 13;
        int k = kc*32 + lk*8 + j;
        apackC[t] = (k < 48) ? f2bf(ec1_w[co*48 + k]) : (unsigned short)0;
    } else if (blk < 2368) {
        // prepack_dt2b
        int t = (blk - 2112)*256 + threadIdx.x;
        int jj = t & 7, lk = (t >> 3) & 3, co = (t >> 5) & 15, j = (t >> 9) & 3, cc = (t >> 11) & 7, p = t >> 14;
        int ci = cc*32 + lk*8 + jj;
        int kh0 = p >> 1, kw0 = p & 1;
        const int dj[4] = {0, 2, 8, 10};
        float v = 0.f;
        if (co < 3) v = dt2_w[(size_t)ci*48 + co*16 + kh0*4 + kw0 + dj[j]];
        apack2[t] = f2bf(v);
    } else if (blk < 2880) {
        // cb_pack
        int t = (blk - 2368)*256 + threadIdx.x;
        cbp[t] = f2bf(cb[t]);
    } else if (blk < 2882) {
        // cb_norm: one code per thread
        int n = (blk - 2880)*256 + threadIdx.x;
        float s = 0.f;
        for (int k = 0; k < 256; ++k) { float v = cb[(size_t)n*256+k]; s = fmaf(v,v,s); }
        cbn[n] = s;
    } else {
        // zero_small
        if (threadIdx.x == 0) sse[0] = 0.f;
        for (int i = threadIdx.x; i < KCB; i += 256) counts[i] = 0;
    }
}

// ---------------- conv1: 3->256, k4, s2, relu -> bf16 NHWC via im2col MFMA; fused GAP partials ----------------
__global__ __launch_bounds__(256) void conv1_mfma(
    const float* __restrict__ x, const unsigned short* __restrict__ apack,
    const float* __restrict__ bias, unsigned short* __restrict__ X0,
    float* __restrict__ poolp) {
    __shared__ float xs[3][18][18];
    __shared__ __align__(16) unsigned short Bm[64*72];
    int b = blockIdx.y, t = blockIdx.x;
    int oh0 = (t >> 3)*8, ow0 = (t & 7)*8;
    int ih0 = oh0*2, iw0 = ow0*2;
    const float* xb = x + (size_t)b*3*128*128;
    for (int i = threadIdx.x; i < 972; i += 256) {
        int c = i / 324, rem = i - c*324, r = rem / 18, cl = rem - r*18;
        int ih = ih0 + r, iw = iw0 + cl;
        xs[c][r][cl] = (ih < 128 && iw < 128) ? xb[((size_t)c*128 + ih)*128 + iw] : 0.f;
    }
    __syncthreads();
    for (int i = threadIdx.x; i < 2048; i += 256) {
        int px = i >> 5, kp = (i & 31)*2;
        int ph = px >> 3, pw = px & 7;
        unsigned int pk = 0;
        #pragma unroll
        for (int u = 0; u < 2; ++u) {
            int k = kp + u;
            float v = 0.f;
            if (k < 48) {
                int c = k >> 4, k2 = k & 15, kh = k2 >> 2, kw = k2 & 3;
                v = xs[c][ph*2+kh][pw*2+kw];
            }
            pk |= ((unsigned int)f2bf(v)) << (16*u);
        }
        *(unsigned int*)&Bm[px*72 + kp] = pk;
    }
    __syncthreads();

    int w = threadIdx.x >> 6, l = threadIdx.x & 63;
    int lr = l & 15, lk = l >> 4;
    f32x4 acc[4][4];
    #pragma unroll
    for (int i = 0; i < 4; ++i)
        #pragma unroll
        for (int j = 0; j < 4; ++j) acc[i][j] = (f32x4){0.f,0.f,0.f,0.f};

    #pragma unroll
    for (int kc = 0; kc < 2; ++kc) {
        short8 bf[4];
        #pragma unroll
        for (int pxf = 0; pxf < 4; ++pxf)
            bf[pxf] = *(const short8*)&Bm[(pxf*16+lr)*72 + kc*32 + lk*8];
        #pragma unroll
        for (int cof = 0; cof < 4; ++cof) {
            int co = w*64 + cof*16 + lr;
            short8 af = *(const short8*)(apack + (((size_t)kc*256 + co)*4 + (size_t)lk)*8);
            acc[cof][0] = __builtin_amdgcn_mfma_f32_16x16x32_bf16(af, bf[0], acc[cof][0], 0, 0, 0);
            acc[cof][1] = __builtin_amdgcn_mfma_f32_16x16x32_bf16(af, bf[1], acc[cof][1], 0, 0, 0);
            acc[cof][2] = __builtin_amdgcn_mfma_f32_16x16x32_bf16(af, bf[2], acc[cof][2], 0, 0, 0);
            acc[cof][3] = __builtin_amdgcn_mfma_f32_16x16x32_bf16(af, bf[3], acc[cof][3], 0, 0, 0);
        }
    }
    float gsum[4][4];
    #pragma unroll
    for (int i = 0; i < 4; ++i)
        #pragma unroll
        for (int j = 0; j < 4; ++j) gsum[i][j] = 0.f;
    #pragma unroll
    for (int cof = 0; cof < 4; ++cof) {
        int cob = w*64 + cof*16 + lk*4;
        float4 bz = *(const float4*)&bias[cob];
        #pragma unroll
        for (int pxf = 0; pxf < 4; ++pxf) {
            int px = pxf*16 + lr;
            int oh = oh0 + (px >> 3), ow = ow0 + (px & 7);
            if (oh < 63 && ow < 63) {
                f32x4 a = acc[cof][pxf];
                float r0 = fmaxf(a.x + bz.x, 0.f);
                float r1 = fmaxf(a.y + bz.y, 0.f);
                float r2 = fmaxf(a.z + bz.z, 0.f);
                float r3 = fmaxf(a.w + bz.w, 0.f);
                gsum[cof][0] += r0; gsum[cof][1] += r1;
                gsum[cof][2] += r2; gsum[cof][3] += r3;
                us4 pk = { f2bf(r0), f2bf(r1), f2bf(r2), f2bf(r3) };
                *(us4*)(X0 + ((size_t)b*HW1 + (size_t)oh*63 + ow)*256 + cob) = pk;
            }
        }
    }
    #pragma unroll
    for (int cof = 0; cof < 4; ++cof)
        #pragma unroll
        for (int j = 0; j < 4; ++j) {
            #pragma unroll
            for (int m = 1; m < 16; m <<= 1)
                gsum[cof][j] += __shfl_xor(gsum[cof][j], m, 64);
        }
    if (lr == 0) {
        float* dst = poolp + ((size_t)b*64 + blockIdx.x)*256;
        #pragma unroll
        for (int cof = 0; cof < 4; ++cof)
            #pragma unroll
            for (int j = 0; j < 4; ++j)
                dst[w*64 + cof*16 + lk*4 + j] = gsum[cof][j] * (1.f/HW1);
    }
}

// ---------------- SE MLP (sums `parts` partial slices) ----------------
__global__ __launch_bounds__(256) void se_mlp(
    const float* __restrict__ pooled, const float* __restrict__ w1,
    const float* __restrict__ b1, const float* __restrict__ w2,
    const float* __restrict__ b2, float* __restrict__ g, int parts) {
    int b = blockIdx.x;
    __shared__ float ps[256], hs[16];
    float s = 0.f;
    for (int k = 0; k < parts; ++k)
        s += pooled[((size_t)b*parts + k)*256 + threadIdx.x];
    ps[threadIdx.x] = s;
    __syncthreads();
    if (threadIdx.x < 16) {
        float a = b1[threadIdx.x];
        const float* wr = w1 + threadIdx.x*256;
        for (int k = 0; k < 256; ++k) a = fmaf(ps[k], wr[k], a);
        hs[threadIdx.x] = fmaxf(a, 0.f);
    }
    __syncthreads();
    float a = b2[threadIdx.x];
    const float* wr = w2 + threadIdx.x*16;
    #pragma unroll
    for (int j = 0; j < 16; ++j) a = fmaf(hs[j], wr[j], a);
    g[b*256 + threadIdx.x] = 1.f / (1.f + expf(-a));
}

// ---------------- channel mean/max of x*g (NHWC bf16) ----------------
__global__ __launch_bounds__(256) void chanpool_nhwc(
    const unsigned short* __restrict__ X, const float* __restrict__ g,
    float* __restrict__ am, int HW) {
    int b = blockIdx.y;
    __shared__ float gs[256];
    gs[threadIdx.x] = g[b*256 + threadIdx.x];
    __syncthreads();
    int p = blockIdx.x*256 + threadIdx.x;
    if (p >= HW) return;
    const unsigned short* xp = X + ((size_t)b*HW + p)*256;
    float s = 0.f, mx = -3.0e38f;
    for (int o = 0; o < 32; ++o) {
        short8 v = *(const short8*)(xp + o*8);
        #pragma unroll
        for (int j = 0; j < 8; ++j) {
            float f = bf2f((unsigned short)v[j]) * gs[o*8+j];
            s += f; mx = fmaxf(mx, f);
        }
    }
    am[((size_t)b*2)*HW + p]   = s * (1.f/256.f);
    am[((size_t)b*2+1)*HW + p] = mx;
}

// ---------------- channel mean/max of x*g (bf16 NCHW, encoder-2 z) ----------------
__global__ __launch_bounds__(256) void chanpool_z(
    const unsigned short* __restrict__ Z, const float* __restrict__ g,
    float* __restrict__ am, int HW) {
    int b = blockIdx.y;
    __shared__ float gs[256];
    gs[threadIdx.x] = g[b*256 + threadIdx.x];
    __syncthreads();
    int p = blockIdx.x*256 + threadIdx.x;
    if (p >= HW) return;
    const unsigned short* xb = Z + (size_t)b*256*HW + p;
    float s = 0.f, mx = -3.0e38f;
    for (int c = 0; c < 256; ++c) {
        float v = bf2f(xb[(size_t)c*HW]) * gs[c];
        s += v; mx = fmaxf(mx, v);
    }
    am[((size_t)b*2)*HW + p]   = s * (1.f/256.f);
    am[((size_t)b*2+1)*HW + p] = mx;
}

// ---------------- 7x7 spatial conv on [mean,max], sigmoid ----------------
__global__ __launch_bounds__(256) void spatial_conv(
    const float* __restrict__ am, const float* __restrict__ sw,
    float* __restrict__ ss, int H, int W, int transpose) {
    int b = blockIdx.y;
    int p = blockIdx.x*256 + threadIdx.x;
    __shared__ float ws[98];
    if (threadIdx.x < 98) {
        int c = threadIdx.x / 49, k = threadIdx.x % 49;
        int kh = k / 7, kw = k % 7;
        ws[threadIdx.x] = transpose ? sw[c*49 + (6-kh)*7 + (6-kw)]
                                    : sw[c*49 + kh*7 + kw];
    }
    __syncthreads();
    if (p >= H*W) return;
    int oh = p / W, ow = p % W;
    float acc = 0.f;
    #pragma unroll
    for (int c = 0; c < 2; ++c) {
        const float* ab = am + ((size_t)b*2 + c)*H*W;
        for (int kh = 0; kh < 7; ++kh) {
            int ih = oh + kh - 3;
            if (ih < 0 || ih >= H) continue;
            for (int kw = 0; kw < 7; ++kw) {
                int iw = ow + kw - 3;
                if (iw < 0 || iw >= W) continue;
                acc = fmaf(ab[(size_t)ih*W + iw], ws[c*49 + kh*7 + kw], acc);
            }
        }
    }
    ss[(size_t)b*H*W + p] = 1.f / (1.f + expf(-acc));
}

// ---------------- IN-PLACE bf16 NCHW: z = z*z*g*sig(s) (encoder-2) ----------------
__global__ __launch_bounds__(256) void cbam_z(
    unsigned short* Z, const float* __restrict__ g,
    const float* __restrict__ ss, int HW) {
    int b = blockIdx.y;
    int e2 = blockIdx.x*256 + threadIdx.x;
    if (e2 >= 128*HW) return;
    size_t e = (size_t)e2*2;
    int c = (int)(e / HW), p = (int)(e % HW);
    float gc = g[b*256 + c];
    float s0 = ss[(size_t)b*HW + p];
    float s1 = ss[(size_t)b*HW + p + 1];
    unsigned int* px = (unsigned int*)(Z + (size_t)b*256*HW + e);
    unsigned int v = *px;
    float f0 = bf2f((unsigned short)(v & 0xffff));
    float f1 = bf2f((unsigned short)(v >> 16));
    f0 = f0*f0*gc*s0;
    f1 = f1*f1*gc*s1;
    *px = (unsigned int)f2bf(f0) | ((unsigned int)f2bf(f1) << 16);
}

// ---------------- bf16 NCHW -> NHWC bf16 (q after VQ) ----------------
__global__ __launch_bounds__(256) void to_nhwc_bf16(
    const unsigned short* __restrict__ Z, unsigned short* __restrict__ X, int HW) {
    int b = blockIdx.y;
    int p = blockIdx.x*256 + threadIdx.x;
    bool valid = p < HW;
    const unsigned short* inb = Z + (size_t)b*256*HW + p;
    unsigned short* dst = X + ((size_t)b*HW + p)*256;
    #pragma unroll
    for (int ch = 0; ch < 4; ++ch) {
        unsigned short buf[64];
        #pragma unroll
        for (int j = 0; j < 64; ++j)
            buf[j] = valid ? inb[(size_t)(ch*64 + j)*HW] : (unsigned short)0;
        if (valid) {
            #pragma unroll
            for (int j2 = 0; j2 < 8; ++j2)
                *(short8*)(dst + ch*64 + j2*8) = *(const short8*)&buf[j2*8];
        }
    }
}

// ---------------- MFMA conv k=2 s=1, NHWC bf16 input, 4x16 tiles, BK=64, XCD swizzle; fused GAP ----------------
// MODE 0: fused input cbam multiply (x*x*g*ss), bf16 NCHW out (conv2 -> z).
// MODE 1: plain input, bf16 NHWC out via LDS-staged epilogue (dt1).
template <int MODE>
__global__ __launch_bounds__(256) void convk2_mfma_nhwc(
    const unsigned short* __restrict__ Xin, const unsigned short* __restrict__ apack,
    const float* __restrict__ bias, const float* __restrict__ gvec,
    const float* __restrict__ ssm, unsigned short* __restrict__ outZ,
    unsigned short* __restrict__ outU,
    float* __restrict__ poolp,
    int inH, int inW, int outH, int outW, int pad) {
    __shared__ __align__(16) unsigned short Sh[MODE ? 16896 : 13600];
    __shared__ float gs[256];
    unsigned short* Ir0 = Sh;
    unsigned short* Ir1 = Sh + 6800;
    int b = blockIdx.y;
    int raw = blockIdx.x;
    int xcd = raw & 7, jj = raw >> 3;
    int t = (xcd + 8*(jj >> 2))*4 + (jj & 3);
    int oh0 = (t >> 2) * 4, ow0 = (t & 3) * 16;
    int w = threadIdx.x >> 6, l = threadIdx.x & 63;
    int lr = l & 15, lk = l >> 4;
    const unsigned short* src = Xin + (size_t)b*inH*inW*256;
    const float* ssb = (MODE == 0) ? (ssm + (size_t)b*inH*inW) : (const float*)0;
    if (MODE == 0) {
        gs[threadIdx.x] = gvec[b*256 + threadIdx.x];
        __syncthreads();
    }

    f32x4 acc[4][4];
    #pragma unroll
    for (int i = 0; i < 4; ++i)
        #pragma unroll
        for (int j = 0; j < 4; ++j) acc[i][j] = (f32x4){0.f,0.f,0.f,0.f};

    auto STAGE = [&](int cc, int bufi) {
        unsigned short* Ib = bufi ? Ir1 : Ir0;
        #pragma unroll
        for (int pass = 0; pass < 3; ++pass) {
            int u = pass*256 + threadIdx.x;
            if (u < 680) {
                int sub = (u >= 340) ? 1 : 0;
                int uu = u - sub*340;
                int sp = uu >> 2, q = uu & 3;
                int r = (sp*241) >> 12, c = sp - r*17;
                int gh = oh0 + r - pad, gw = ow0 + c - pad;
                short8 v = (short8){0,0,0,0,0,0,0,0};
                bool valid = (gh >= 0) && (gh < inH) && (gw >= 0) && (gw < inW);
                if (valid)
                    v = *(const short8*)(src + ((size_t)gh*inW + gw)*256 + (cc+sub)*32 + q*8);
                if (MODE == 0) {
                    if (valid) {
                        float sv = ssb[(size_t)gh*inW + gw];
                        int c0 = (cc+sub)*32 + q*8;
                        unsigned int pk[4];
                        #pragma unroll
                        for (int j = 0; j < 4; ++j) {
                            float f0 = bf2f((unsigned short)v[2*j]);
                            float f1 = bf2f((unsigned short)v[2*j+1]);
                            f0 = f0*f0*gs[c0+2*j]*sv;
                            f1 = f1*f1*gs[c0+2*j+1]*sv;
                            pk[j] = (unsigned int)f2bf(f0) | ((unsigned int)f2bf(f1) << 16);
                        }
                        v = *(const short8*)pk;
                    }
                }
                *(short8*)&Ib[sub*3400 + sp*40 + q*8] = v;
            }
        }
    };

    STAGE(0, 0);
    for (int cc = 0; cc < 8; cc += 2) {
        __syncthreads();
        if (cc < 6) STAGE(cc+2, ((cc >> 1) + 1) & 1);
        const unsigned short* Ibase = ((cc >> 1) & 1) ? Ir1 : Ir0;
        #pragma unroll
        for (int half = 0; half < 2; ++half) {
            const unsigned short* Ib = Ibase + half*3400;
            #pragma unroll
            for (int tap = 0; tap < 4; ++tap) {
                int kh = tap >> 1, kw = tap & 1;
                int spb = kh*17 + kw + lr;
                short8 b0 = *(const short8*)&Ib[(spb     )*40 + lk*8];
                short8 b1 = *(const short8*)&Ib[(spb + 17)*40 + lk*8];
                short8 b2 = *(const short8*)&Ib[(spb + 34)*40 + lk*8];
                short8 b3 = *(const short8*)&Ib[(spb + 51)*40 + lk*8];
                const unsigned short* abase = apack + (((size_t)((cc+half)*4 + tap)*256)*4 + (size_t)lk)*8;
                #pragma unroll
                for (int cof = 0; cof < 4; ++cof) {
                    int co = w*64 + cof*16 + lr;
                    short8 af = *(const short8*)(abase + (size_t)co*32);
                    acc[cof][0] = __builtin_amdgcn_mfma_f32_16x16x32_bf16(af, b0, acc[cof][0], 0, 0, 0);
                    acc[cof][1] = __builtin_amdgcn_mfma_f32_16x16x32_bf16(af, b1, acc[cof][1], 0, 0, 0);
                    acc[cof][2] = __builtin_amdgcn_mfma_f32_16x16x32_bf16(af, b2, acc[cof][2], 0, 0, 0);
                    acc[cof][3] = __builtin_amdgcn_mfma_f32_16x16x32_bf16(af, b3, acc[cof][3], 0, 0, 0);
                }
            }
        }
    }
    float gsum[4][4];
    #pragma unroll
    for (int i = 0; i < 4; ++i)
        #pragma unroll
        for (int j = 0; j < 4; ++j) gsum[i][j] = 0.f;
    int ow = ow0 + lr;
    if (MODE == 0) {
        #pragma unroll
        for (int cof = 0; cof < 4; ++cof) {
            int cob = w*64 + cof*16 + lk*4;
            float4 bz = *(const float4*)&bias[cob];
            #pragma unroll
            for (int pxf = 0; pxf < 4; ++pxf) {
                int oh = oh0 + pxf;
                if (oh < outH && ow < outW) {
                    f32x4 a = acc[cof][pxf];
                    float r0 = fmaxf(a.x + bz.x, 0.f);
                    float r1 = fmaxf(a.y + bz.y, 0.f);
                    float r2 = fmaxf(a.z + bz.z, 0.f);
                    float r3 = fmaxf(a.w + bz.w, 0.f);
                    gsum[cof][0] += r0; gsum[cof][1] += r1;
                    gsum[cof][2] += r2; gsum[cof][3] += r3;
                    size_t base = ((size_t)(b*256 + cob)*outH + oh)*outW + ow;
                    size_t st = (size_t)outH*outW;
                    outZ[base]        = f2bf(r0);
                    outZ[base +   st] = f2bf(r1);
                    outZ[base + 2*st] = f2bf(r2);
                    outZ[base + 3*st] = f2bf(r3);
                }
            }
        }
    } else {
        __syncthreads();
        #pragma unroll
        for (int cof = 0; cof < 4; ++cof) {
            int cob = w*64 + cof*16 + lk*4;
            float4 bz = *(const float4*)&bias[cob];
            #pragma unroll
            for (int pxf = 0; pxf < 4; ++pxf) {
                f32x4 a = acc[cof][pxf];
                float r0 = fmaxf(a.x + bz.x, 0.f);
                float r1 = fmaxf(a.y + bz.y, 0.f);
                float r2 = fmaxf(a.z + bz.z, 0.f);
                float r3 = fmaxf(a.w + bz.w, 0.f);
                int oh = oh0 + pxf;
                if (oh < outH && ow < outW) {
                    gsum[cof][0] += r0; gsum[cof][1] += r1;
                    gsum[cof][2] += r2; gsum[cof][3] += r3;
                }
                us4 pk = { f2bf(r0), f2bf(r1), f2bf(r2), f2bf(r3) };
                *(us4*)&Sh[(pxf*16 + lr)*264 + cob] = pk;
            }
        }
        __syncthreads();
        int owp = threadIdx.x >> 4, c0 = (threadIdx.x & 15)*16;
        int oww = ow0 + owp;
        #pragma unroll
        for (int row = 0; row < 4; ++row) {
            int oh = oh0 + row;
            if (oh < outH && oww < outW) {
                unsigned short* dst = outU + (((size_t)b*outH + oh)*outW + oww)*256 + c0;
                *(short8*)dst       = *(const short8*)&Sh[(row*16 + owp)*264 + c0];
                *(short8*)(dst + 8) = *(const short8*)&Sh[(row*16 + owp)*264 + c0 + 8];
            }
        }
    }
    #pragma unroll
    for (int cof = 0; cof < 4; ++cof)
        #pragma unroll
        for (int j = 0; j < 4; ++j) {
            #pragma unroll
            for (int m = 1; m < 16; m <<= 1)
                gsum[cof][j] += __shfl_xor(gsum[cof][j], m, 64);
        }
    if (lr == 0) {
        float inv = 1.f / (float)(outH * outW);
        float* dst = poolp + ((size_t)b*64 + raw)*256;
        #pragma unroll
        for (int cof = 0; cof < 4; ++cof)
            #pragma unroll
            for (int j = 0; j < 4; ++j)
                dst[w*64 + cof*16 + lk*4 + j] = gsum[cof][j] * inv;
    }
}

// ---------------- MFMA VQ assign: bf16 z, LDS-staged codebook, 64 rows/block ----------------
__global__ __launch_bounds__(256) void vq_assign_mfma(
    const unsigned short* __restrict__ z, const unsigned short* __restrict__ cbp,
    const float* __restrict__ cbn, int* __restrict__ idx) {
    __shared__ __align__(16) unsigned short zb[64*264];
    __shared__ __align__(16) unsigned short cbs[2][32*264];
    __shared__ float cbl[KCB];
    int r0 = blockIdx.x * 64;
    for (int v = threadIdx.x; v < 2048; v += 256) {
        int row = v >> 5, o = v & 31;
        *(short8*)&zb[row*264 + o*8] = *(const short8*)&z[(size_t)(r0+row)*256 + o*8];
    }
    for (int i = threadIdx.x; i < KCB; i += 256) cbl[i] = cbn[i];
    int tcode = threadIdx.x >> 3, tk = threadIdx.x & 7;
    auto STAGE_CB = [&](int c, int bufi) {
        const unsigned short* src = cbp + ((size_t)(c*32 + tcode))*256 + tk*8;
        unsigned short* dst = &cbs[bufi][tcode*264 + tk*8];
        #pragma unroll
        for (int j = 0; j < 4; ++j)
            *(short8*)(dst + j*64) = *(const short8*)(src + j*64);
    };
    STAGE_CB(0, 0);
    __syncthreads();

    int w = threadIdx.x >> 6, l = threadIdx.x & 63;
    int lr = l & 15, lk = l >> 4;
    short8 afr[8];
    #pragma unroll
    for (int ks = 0; ks < 8; ++ks)
        afr[ks] = *(const short8*)&zb[(w*16 + lr)*264 + ks*32 + lk*8];

    float bd[4]; int bi[4];
    #pragma unroll
    for (int r = 0; r < 4; ++r) { bd[r] = 3.0e38f; bi[r] = 0; }

    for (int c = 0; c < 16; ++c) {
        if (c < 15) STAGE_CB(c+1, (c+1)&1);
        const unsigned short* Cb = cbs[c & 1];
        #pragma unroll
        for (int f = 0; f < 2; ++f) {
            f32x4 acc = (f32x4){0.f,0.f,0.f,0.f};
            #pragma unroll
            for (int ks = 0; ks < 8; ++ks) {
                short8 bfr = *(const short8*)&Cb[(f*16 + lr)*264 + ks*32 + lk*8];
                acc = __builtin_amdgcn_mfma_f32_16x16x32_bf16(afr[ks], bfr, acc, 0, 0, 0);
            }
            int n = c*32 + f*16 + lr;
            float cn = cbl[n];
            #pragma unroll
            for (int r = 0; r < 4; ++r) {
                float dist = fmaf(-2.f, acc[r], cn);
                if (dist < bd[r]) { bd[r] = dist; bi[r] = n; }
            }
        }
        __syncthreads();
    }
    #pragma unroll
    for (int r = 0; r < 4; ++r) {
        #pragma unroll
        for (int off = 1; off < 16; off <<= 1) {
            float od = __shfl_xor(bd[r], off, 64);
            int   oi = __shfl_xor(bi[r], off, 64);
            if (od < bd[r] || (od == bd[r] && oi < bi[r])) { bd[r] = od; bi[r] = oi; }
        }
    }
    if (lr == 0) {
        #pragma unroll
        for (int r = 0; r < 4; ++r)
            idx[r0 + w*16 + lk*4 + r] = bi[r];
    }
}

// ---------------- IN-PLACE VQ gather (bf16 z -> bf16 q) ----------------
__global__ __launch_bounds__(256) void vq_gather(
    unsigned short* zq, const float* __restrict__ cb,
    const int* __restrict__ idx, float* __restrict__ sse, int* __restrict__ counts) {
    __shared__ int hist[KCB];
    for (int i = threadIdx.x; i < KCB; i += 256) hist[i] = 0;
    __syncthreads();
    float local = 0.f;
    for (int r = blockIdx.x; r < NROWS; r += GATHER_BLOCKS) {
        int id = idx[r];
        if (threadIdx.x == 0) atomicAdd(&hist[id], 1);
        float qv = cb[(size_t)id*256 + threadIdx.x];
        unsigned short* pz = zq + (size_t)r*256 + threadIdx.x;
        float zv = bf2f(*pz);
        *pz = f2bf(qv);
        float d = qv - zv;
        local = fmaf(d, d, local);
    }
    __shared__ float lds[4];
    for (int off = 32; off; off >>= 1) local += __shfl_down(local, off, 64);
    if ((threadIdx.x & 63) == 0) lds[threadIdx.x >> 6] = local;
    __syncthreads();
    if (threadIdx.x == 0) atomicAdd(sse, lds[0]+lds[1]+lds[2]+lds[3]);
    for (int i = threadIdx.x; i < KCB; i += 256) {
        int h = hist[i];
        if (h) atomicAdd(counts + i, h);
    }
}

// ---------------- loss + perplexity ----------------
__global__ __launch_bounds__(256) void vq_finalize(
    const float* __restrict__ sse, const int* __restrict__ counts,
    float* __restrict__ out) {
    __shared__ float lds[4];
    float h = 0.f;
    for (int n = threadIdx.x; n < KCB; n += 256) {
        float p = (float)counts[n] * (1.f/123008.f);
        h += p * logf(p + 1e-10f);
    }
    for (int off = 32; off; off >>= 1) h += __shfl_down(h, off, 64);
    if ((threadIdx.x & 63) == 0) lds[threadIdx.x >> 6] = h;
    __syncthreads();
    if (threadIdx.x == 0) {
        out[1572864] = 1.25f * sse[0] / 31490048.f;
        out[1572865] = expf(-(lds[0]+lds[1]+lds[2]+lds[3]));
    }
}

// ---------------- dt2 via parity-split MFMA, fused input cbam multiply ----------------
__global__ __launch_bounds__(256) void dt2_mfma(
    const unsigned short* __restrict__ Y, const unsigned short* __restrict__ apack,
    const float* __restrict__ bias, const float* __restrict__ gvec,
    const float* __restrict__ ssm, float* __restrict__ out) {
    __shared__ __align__(16) unsigned short Iraw[2][289*40];
    __shared__ float gs[256];
    int b = blockIdx.y, t = blockIdx.x;
    int a0 = (t >> 2)*16, b0 = (t & 3)*16;
    int p = threadIdx.x >> 6;
    int l = threadIdx.x & 63;
    int lr = l & 15, lk = l >> 4;
    const unsigned short* src = Y + (size_t)b*HW1*256;
    const float* ssb = ssm + (size_t)b*HW1;
    gs[threadIdx.x] = gvec[b*256 + threadIdx.x];
    __syncthreads();

    auto STAGE = [&](int cc, int bufi) {
        #pragma unroll
        for (int pass = 0; pass < 5; ++pass) {
            int u = pass*256 + threadIdx.x;
            if (u < 1156) {
                int sp = u >> 2, q = u & 3;
                int r = (sp*241) >> 12, c = sp - r*17;
                int ia = a0 - 1 + r, ib = b0 - 1 + c;
                short8 v = (short8){0,0,0,0,0,0,0,0};
                bool valid = (ia >= 0) && (ia < 63) && (ib >= 0) && (ib < 63);
                if (valid) {
                    v = *(const short8*)(src + ((size_t)ia*63 + ib)*256 + cc*32 + q*8);
                    float sv = ssb[(size_t)ia*63 + ib];
                    int c0 = cc*32 + q*8;
                    unsigned int pk[4];
                    #pragma unroll
                    for (int j = 0; j < 4; ++j) {
                        float f0 = bf2f((unsigned short)v[2*j]);
                        float f1 = bf2f((unsigned short)v[2*j+1]);
                        f0 = f0*f0*gs[c0+2*j]*sv;
                        f1 = f1*f1*gs[c0+2*j+1]*sv;
                        pk[j] = (unsigned int)f2bf(f0) | ((unsigned int)f2bf(f1) << 16);
                    }
                    v = *(const short8*)pk;
                }
                *(short8*)&Iraw[bufi][sp*40 + q*8] = v;
            }
        }
    };

    f32x4 acc[16];
    #pragma unroll
    for (int i = 0; i < 16; ++i) acc[i] = (f32x4){0.f,0.f,0.f,0.f};

    STAGE(0, 0);
    for (int cc = 0; cc < 8; ++cc) {
        __syncthreads();
        if (cc < 7) STAGE(cc+1, (cc+1)&1);
        const unsigned short* Ib = Iraw[cc & 1];
        #pragma unroll
        for (int j = 0; j < 4; ++j) {
            int jh = j >> 1, jw = j & 1;
            short8 af = *(const short8*)(apack +
                ((size_t)((p*8 + cc)*4 + j))*512 + lr*32 + lk*8);
            int sp0 = (1 - jh)*17 + (lr + 1 - jw);
            #pragma unroll
            for (int nf = 0; nf < 16; ++nf) {
                short8 bf = *(const short8*)&Ib[(sp0 + nf*17)*40 + lk*8];
                acc[nf] = __builtin_amdgcn_mfma_f32_16x16x32_bf16(af, bf, acc[nf], 0, 0, 0);
            }
        }
    }
    if (lk == 0) {
        int kh0 = p >> 1, kw0 = p & 1;
        float bz0 = bias[0], bz1 = bias[1], bz2 = bias[2];
        int wp = 2*(b0 + lr) + kw0;
        #pragma unroll
        for (int nf = 0; nf < 16; ++nf) {
            int h = 2*(a0 + nf) + kh0;
            size_t ob = (size_t)(b*3)*16384 + (size_t)h*128 + wp;
            out[ob]         = acc[nf].x + bz0;
            out[ob + 16384] = acc[nf].y + bz1;
            out[ob + 32768] = acc[nf].z + bz2;
        }
    }
}

// ---------------- launch ----------------
extern "C" void kernel_launch(void* const* d_in, const int* in_sizes, int n_in,
                              void* d_out, int out_size, void* d_ws, size_t ws_size,
                              hipStream_t stream) {
    const float* x      = (const float*)d_in[0];
    const float* ec1_w  = (const float*)d_in[1];
    const float* ec1_b  = (const float*)d_in[2];
    const float* ec2_w  = (const float*)d_in[3];
    const float* ec2_b  = (const float*)d_in[4];
    const float* se1_w1 = (const float*)d_in[5];
    const float* se1_b1 = (const float*)d_in[6];
    const float* se1_w2 = (const float*)d_in[7];
    const float* se1_b2 = (const float*)d_in[8];
    const float* sa1_w  = (const float*)d_in[9];
    const float* se2_w1 = (const float*)d_in[10];
    const float* se2_b1 = (const float*)d_in[11];
    const float* se2_w2 = (const float*)d_in[12];
    const float* se2_b2 = (const float*)d_in[13];
    const float* sa2_w  = (const float*)d_in[14];
    const float* cbk    = (const float*)d_in[15];
    const float* dt1_w  = (const float*)d_in[16];
    const float* dt1_b  = (const float*)d_in[17];
    const float* dt2_w  = (const float*)d_in[18];
    const float* dt2_b  = (const float*)d_in[19];
    const float* dse_w1 = (const float*)d_in[20];
    const float* dse_b1 = (const float*)d_in[21];
    const float* dse_w2 = (const float*)d_in[22];
    const float* dse_b2 = (const float*)d_in[23];
    const float* dsa_w  = (const float*)d_in[24];
    float* out = (float*)d_out;

    unsigned short* Zb = (unsigned short*)d_ws;           // T62 bf16 NCHW z/q (63 MB)
    unsigned short* U0 = Zb + T62;                         // T63 bf16 NHWC (65 MB)
    unsigned short* U1 = U0 + T63;                         // T63 bf16 NHWC (65 MB)
    float* pooled = (float*)(U1 + T63);                    // 32*64*256 floats (2 MB partials)
    float* g      = pooled + 524288;
    float* am     = g + 8192;
    float* ssmap  = am + (size_t)NB*2*HW1;
    float* cbn    = ssmap + (size_t)NB*HW1;
    unsigned short* apackE = (unsigned short*)(cbn + 512);
    unsigned short* apackD = apackE + 262144;
    unsigned short* cbp    = apackD + 262144;
    unsigned short* apackC = cbp + 131072;
    unsigned short* apack2 = apackC + 16384;
    float* sse    = (float*)(apack2 + 65536);
    int*   counts = (int*)(sse + 1);
    int*   idx    = counts + 512;

    // fused prep (all prepacks + codebook pack/norm + zeroing) in one dispatch
    prep_all<<<2883, 256, 0, stream>>>(ec2_w, apackE, dt1_w, apackD, ec1_w, apackC,
                                       dt2_w, apack2, cbk, cbp, cbn, sse, counts);

    // encoder conv1 (MFMA im2col, fused GAP) -> U0 bf16 NHWC; cbam1 stats on U0
    conv1_mfma<<<dim3(64, NB), 256, 0, stream>>>(x, apackC, ec1_b, U0, pooled);
    se_mlp<<<NB, 256, 0, stream>>>(pooled, se1_w1, se1_b1, se1_w2, se1_b2, g, 64);
    chanpool_nhwc<<<dim3(16, NB), 256, 0, stream>>>(U0, g, am, HW1);
    spatial_conv<<<dim3(16, NB), 256, 0, stream>>>(am, sa1_w, ssmap, 63, 63, 0);
    // cbam1 final multiply FUSED into conv2 staging

    // conv2 (U0 -> Zb bf16 NCHW, fused cbam1 multiply + fused GAP) + cbam2 stats => z in Zb
    convk2_mfma_nhwc<0><<<dim3(64, NB), 256, 0, stream>>>(U0, apackE, ec2_b, g, ssmap, Zb, (unsigned short*)0, pooled, 63, 63, 62, 62, 0);
    se_mlp<<<NB, 256, 0, stream>>>(pooled, se2_w1, se2_b1, se2_w2, se2_b2, g, 64);
    chanpool_z<<<dim3(16, NB), 256, 0, stream>>>(Zb, g, am, HW2);
    spatial_conv<<<dim3(16, NB), 256, 0, stream>>>(am, sa2_w, ssmap, 62, 62, 0);
    cbam_z<<<dim3(1922, NB), 256, 0, stream>>>(Zb, g, ssmap, HW2);

    // VQ: z in Zb -> q in Zb (in-place bf16), then q -> U1 bf16 NHWC
    vq_assign_mfma<<<NROWS/64, 256, 0, stream>>>(Zb, cbp, cbn, idx);
    vq_gather<<<GATHER_BLOCKS, 256, 0, stream>>>(Zb, cbk, idx, sse, counts);
    vq_finalize<<<1, 256, 0, stream>>>(sse, counts, out);
    to_nhwc_bf16<<<dim3(16, NB), 256, 0, stream>>>(Zb, U1, HW2);

    // decoder dt1 (U1 -> U0 bf16 NHWC, fused GAP) + cbam3 stats on U0
    convk2_mfma_nhwc<1><<<dim3(64, NB), 256, 0, stream>>>(U1, apackD, dt1_b, (const float*)0, (const float*)0, (unsigned short*)0, U0, pooled, 62, 62, 63, 63, 1);
    se_mlp<<<NB, 256, 0, stream>>>(pooled, dse_w1, dse_b1, dse_w2, dse_b2, g, 64);
    chanpool_nhwc<<<dim3(16, NB), 256, 0, stream>>>(U0, g, am, HW1);
    spatial_conv<<<dim3(16, NB), 256, 0, stream>>>(am, dsa_w, ssmap, 63, 63, 1);
    // cbam3 final multiply FUSED into dt2 staging

    // final convT (parity-split MFMA, fused cbam3 multiply) -> out
    dt2_mfma<<<dim3(16, NB), 256, 0, stream>>>(U0, apack2, dt2_b, g, ssmap, out);
}